// Round 6
// baseline (417.823 us; speedup 1.0000x reference)
//
#include <hip/hip_runtime.h>

#define N_NODES 100000
#define N_EDGES 1600000

#define NBK 782    // row buckets of 128 rows: ceil(100000/128)
#define EPB 8192   // edges per binA block
#define NBA 196    // binA blocks: 196*8192 = 1,605,632 >= N_EDGES
#define CAPE 4096  // LDS edge-stage capacity in binB (mean bucket = 2046)

typedef __attribute__((ext_vector_type(8))) short short8;
typedef __attribute__((ext_vector_type(4))) float f32x4;

__device__ __forceinline__ ushort f2bf(float f) {
    uint u = __float_as_uint(f);
    return (ushort)((u + 0x7fff + ((u >> 16) & 1)) >> 16);   // RNE
}
__device__ __forceinline__ float bflo(uint p) { return __uint_as_float(p << 16); }
__device__ __forceinline__ float bfhi(uint p) { return __uint_as_float(p & 0xffff0000u); }

// ---------------- CSR build: two-pass counting sort by 128-row bucket ----------------

__global__ void __launch_bounds__(1024) binA_k(const int* __restrict__ row,
                                               const int* __restrict__ col,
                                               const float* __restrict__ vals,
                                               int2* __restrict__ tmp,
                                               int* __restrict__ gcount,
                                               int* __restrict__ offT) {
    __shared__ int h[NBK];
    __shared__ int cur[NBK];
    __shared__ int sh[1024];
    int t = threadIdx.x;
    int base = blockIdx.x * EPB;

    // stage 8 edges/thread in registers (row/col/vals each read exactly once)
    int rr[8], cc[8];
    float vv[8];
#pragma unroll
    for (int u = 0; u < 8; ++u) {
        int e = base + u * 1024 + t;
        bool ok = (e < N_EDGES);
        rr[u] = ok ? row[e] : -1;
        cc[u] = ok ? col[e] : 0;
        vv[u] = ok ? vals[e] : 0.f;
    }

    if (t < NBK) h[t] = 0;
    __syncthreads();
#pragma unroll
    for (int u = 0; u < 8; ++u)
        if (rr[u] >= 0) atomicAdd(&h[rr[u] >> 7], 1);
    __syncthreads();
    if (t < NBK && h[t]) atomicAdd(&gcount[t], h[t]);
    // exclusive scan of h over NBK (padded to 1024)
    sh[t] = (t < NBK) ? h[t] : 0;
    __syncthreads();
    for (int off = 1; off < 1024; off <<= 1) {
        int v = (t >= off) ? sh[t - off] : 0;
        __syncthreads();
        sh[t] += v;
        __syncthreads();
    }
    if (t < NBK) {
        int ex = t ? sh[t - 1] : 0;
        cur[t] = ex;
        offT[t * NBA + blockIdx.x] = ex;
    }
    if (t == NBK - 1) offT[NBK * NBA + blockIdx.x] = sh[t];  // row NBK = edges in block
    __syncthreads();
    // scatter into block-private region, grouped by bucket
#pragma unroll
    for (int u = 0; u < 8; ++u) {
        if (rr[u] >= 0) {
            int p = atomicAdd(&cur[rr[u] >> 7], 1);
            int2 v;
            v.x = ((rr[u] & 127) << 17) | cc[u];   // 7-bit row-in-bucket | 17-bit col
            v.y = __float_as_int(vv[u]);
            tmp[base + p] = v;
        }
    }
}

// exclusive scan of the 782 bucket totals -> bstart (NBK+1 entries); rowptr[N] = E
__global__ void __launch_bounds__(1024) bscan_k(const int* __restrict__ gcount,
                                                int* __restrict__ bstart,
                                                int* __restrict__ rowptr) {
    __shared__ int sh[1024];
    int t = threadIdx.x;
    sh[t] = (t < NBK) ? gcount[t] : 0;
    __syncthreads();
    for (int off = 1; off < 1024; off <<= 1) {
        int v = (t >= off) ? sh[t - off] : 0;
        __syncthreads();
        sh[t] += v;
        __syncthreads();
    }
    if (t < NBK) bstart[t] = t ? sh[t - 1] : 0;
    if (t == 0) { bstart[NBK] = N_EDGES; rowptr[N_NODES] = N_EDGES; }
}

// Phase B: one block per bucket; flat-index gather, LDS stage, scatter from LDS.
// ep keeps the (rib<<17)|col encoding — spmm2 consumes rib directly.

__global__ void __launch_bounds__(256) binB_k(const int2* __restrict__ tmp,
                                              const int* __restrict__ offT,
                                              const int* __restrict__ bstart,
                                              int* __restrict__ rowptr,
                                              int2* __restrict__ ep) {
    __shared__ int goff[NBA];
    __shared__ int sstart[NBA];
    __shared__ int s_scan[256];
    __shared__ int h[128];
    __shared__ int cur[128];
    __shared__ int2 ebuf[CAPE];
    __shared__ int sT;
    int b = blockIdx.x, t = threadIdx.x;

    int c = 0;
    if (t < NBA) {
        int o0 = offT[b * NBA + t];
        int o1 = offT[(b + 1) * NBA + t];
        c = o1 - o0;
        goff[t] = t * EPB + o0;
    }
    s_scan[t] = c;
    __syncthreads();
    for (int off = 1; off < 256; off <<= 1) {
        int v = (t >= off) ? s_scan[t - off] : 0;
        __syncthreads();
        s_scan[t] += v;
        __syncthreads();
    }
    if (t < NBA) sstart[t] = s_scan[t] - c;
    if (t == NBA - 1) sT = s_scan[t];
    if (t < 128) h[t] = 0;
    __syncthreads();
    int T = sT;

    // load + histogram + stage
    for (int j = t; j < T; j += 256) {
        int lo = 0, hi = NBA - 1;            // last s with sstart[s] <= j
        while (lo < hi) {
            int mid = (lo + hi + 1) >> 1;
            if (sstart[mid] <= j) lo = mid; else hi = mid - 1;
        }
        int2 v = tmp[goff[lo] + (j - sstart[lo])];
        atomicAdd(&h[v.x >> 17], 1);
        if (j < CAPE) ebuf[j] = v;
    }
    __syncthreads();
    // exclusive scan over 128 bins
    for (int off = 1; off < 128; off <<= 1) {
        int v = (t >= off && t < 128) ? h[t - off] : 0;
        __syncthreads();
        if (t < 128) h[t] += v;
        __syncthreads();
    }
    int bs = bstart[b];
    if (t < 128) {
        int ex = t ? h[t - 1] : 0;
        cur[t] = ex;
        int r = (b << 7) + t;
        if (r < N_NODES) rowptr[r] = bs + ex;
    }
    __syncthreads();
    // scatter to final CSR positions (from LDS; overflow re-reads global)
    for (int j = t; j < T; j += 256) {
        int2 v;
        if (j < CAPE) v = ebuf[j];
        else {
            int lo = 0, hi = NBA - 1;
            while (lo < hi) {
                int mid = (lo + hi + 1) >> 1;
                if (sstart[mid] <= j) lo = mid; else hi = mid - 1;
            }
            v = tmp[goff[lo] + (j - sstart[lo])];
        }
        int p = atomicAdd(&cur[v.x >> 17], 1);
        ep[bs + p] = v;                      // keep rib bits for spmm2
    }
}

// ---------------- converts ----------------

// transpose-convert all three weight matrices: Wt[n][k] = bf16(W[k][n])
__global__ void wcvt_k(const float* __restrict__ W1, const float* __restrict__ W2,
                       const float* __restrict__ W3, ushort* __restrict__ Wt1,
                       ushort* __restrict__ Wt2, ushort* __restrict__ Wt3) {
    int i = blockIdx.x * 256 + threadIdx.x;
    if (i < 16384) {
        int n = i >> 7, k = i & 127;
        Wt1[i] = f2bf(W1[k * 128 + n]);
        Wt2[i] = f2bf(W2[k * 128 + n]);
    }
    if (i < 8192) {
        int n = i >> 7, k = i & 127;
        Wt3[i] = f2bf(W3[k * 64 + n]);
    }
}

// ---------------- GEMM: Y[r, 0..DN) = bf16( X[r,:] @ Wt^T + bias ) ----------------

template <int DN, bool AF32>
__global__ void __launch_bounds__(256) gemm_k(const void* __restrict__ Xa,
                                              const ushort* __restrict__ Wt,
                                              const float* __restrict__ bias,
                                              ushort* __restrict__ Y) {
    constexpr int NT = DN / 16;
    const ushort* Xb = (const ushort*)Xa;
    const float* Xf = (const float*)Xa;
    int wv = threadIdx.x >> 6;
    int l = threadIdx.x & 63;
    int lg = l >> 4, lm = l & 15;
    int rbase = blockIdx.x * 64 + wv * 16;

    int arow = rbase + lm;
    if (arow > N_NODES - 1) arow = N_NODES - 1;     // clamp (stores predicated)

    f32x4 acc[NT];
#pragma unroll
    for (int n = 0; n < NT; n++) acc[n] = (f32x4){0.f, 0.f, 0.f, 0.f};

#pragma unroll
    for (int kk = 0; kk < 4; ++kk) {
        short8 a;
        if constexpr (AF32) {
            const float* ap = Xf + (size_t)arow * 128 + kk * 32 + lg * 8;
            float4 u = *(const float4*)ap;
            float4 v = *(const float4*)(ap + 4);
            a = (short8){(short)f2bf(u.x), (short)f2bf(u.y), (short)f2bf(u.z), (short)f2bf(u.w),
                         (short)f2bf(v.x), (short)f2bf(v.y), (short)f2bf(v.z), (short)f2bf(v.w)};
        } else {
            a = *(const short8*)(Xb + (size_t)arow * 128 + kk * 32 + lg * 8);
        }
#pragma unroll
        for (int n = 0; n < NT; ++n) {
            short8 b = *(const short8*)(Wt + (size_t)(n * 16 + lm) * 128 + kk * 32 + lg * 8);
            acc[n] = __builtin_amdgcn_mfma_f32_16x16x32_bf16(a, b, acc[n], 0, 0, 0);
        }
    }

    int r0 = rbase + lg * 4;
#pragma unroll
    for (int n = 0; n < NT; ++n) {
        int c = n * 16 + lm;
        float bj = bias[c];
#pragma unroll
        for (int i = 0; i < 4; ++i) {
            int r = r0 + i;
            if (r < N_NODES) Y[(size_t)r * DN + c] = f2bf(acc[n][i] + bj);
        }
    }
}

// ---------------- SpMM v2: edge-parallel, LDS-accumulate per 128-row bucket ----------
// One block per bucket (x2 half-dim blocks for D=128). 32 groups of 8 lanes; each
// group owns an equal span of the bucket's row-sorted edges. Lane gathers uint4
// (8 dims); accumulates in registers while rib is unchanged (row-sorted -> transition
// every ~16 edges); flushes via LDS atomicAdd. No rowptr, no degree divergence, no
// per-row dependent chains: gathers stream 4-deep per group continuously.

template <int D, bool RELU>
__global__ void __launch_bounds__(256) spmm2_k(const int* __restrict__ bstart,
                                               const int2* __restrict__ ep,
                                               const ushort* __restrict__ xb,
                                               void* __restrict__ y) {
    constexpr int DW = 64;                    // dims per block
    __shared__ float acc[128 * DW];           // 32 KB
    int bid = blockIdx.x;
    int b    = (D == 128) ? (bid >> 1) : bid;
    int half = (D == 128) ? (bid & 1)  : 0;
    int t = threadIdx.x;
    for (int i = t; i < 128 * DW / 4; i += 256)
        ((float4*)acc)[i] = (float4){0.f, 0.f, 0.f, 0.f};
    __syncthreads();

    int s = bstart[b], e = bstart[b + 1];
    int g = t >> 3, hl = t & 7;               // 32 groups of 8 lanes
    int T = e - s;
    int sp = (T + 31) >> 5;
    int js = s + g * sp;
    int je = js + sp; if (je > e) je = e;

    const uint4* xp = (const uint4*)xb;
    constexpr int RS = (D == 128) ? 16 : 8;   // source row stride in uint4
    int xoff = (D == 128) ? half * 8 + hl : hl;

    float a0 = 0.f, a1 = 0.f, a2 = 0.f, a3 = 0.f;
    float a4 = 0.f, a5 = 0.f, a6 = 0.f, a7 = 0.f;
    int crib = -1;
    float* ab = acc + hl * 8;

#define PROC(E, X) {                                                        \
    int rib = (E).x >> 17;                                                  \
    if (rib != crib) {                                                      \
        if (crib >= 0) {                                                    \
            float* p = ab + crib * DW;                                      \
            atomicAdd(p + 0, a0); atomicAdd(p + 1, a1);                     \
            atomicAdd(p + 2, a2); atomicAdd(p + 3, a3);                     \
            atomicAdd(p + 4, a4); atomicAdd(p + 5, a5);                     \
            atomicAdd(p + 6, a6); atomicAdd(p + 7, a7);                     \
        }                                                                   \
        crib = rib;                                                         \
        a0 = a1 = a2 = a3 = a4 = a5 = a6 = a7 = 0.f;                        \
    }                                                                       \
    float v = __int_as_float((E).y);                                        \
    a0 = fmaf(v, bflo((X).x), a0); a1 = fmaf(v, bfhi((X).x), a1);           \
    a2 = fmaf(v, bflo((X).y), a2); a3 = fmaf(v, bfhi((X).y), a3);           \
    a4 = fmaf(v, bflo((X).z), a4); a5 = fmaf(v, bfhi((X).z), a5);           \
    a6 = fmaf(v, bflo((X).w), a6); a7 = fmaf(v, bfhi((X).w), a7); }

    int j = js;
    for (; j + 4 <= je; j += 4) {             // 4 independent gathers in flight/group
        int2 e0 = ep[j], e1 = ep[j + 1], e2 = ep[j + 2], e3 = ep[j + 3];
        uint4 x0 = xp[(e0.x & 0x1ffff) * RS + xoff];
        uint4 x1 = xp[(e1.x & 0x1ffff) * RS + xoff];
        uint4 x2 = xp[(e2.x & 0x1ffff) * RS + xoff];
        uint4 x3 = xp[(e3.x & 0x1ffff) * RS + xoff];
        PROC(e0, x0) PROC(e1, x1) PROC(e2, x2) PROC(e3, x3)
    }
    for (; j < je; ++j) {
        int2 e0 = ep[j];
        uint4 x0 = xp[(e0.x & 0x1ffff) * RS + xoff];
        PROC(e0, x0)
    }
    if (crib >= 0) {
        float* p = ab + crib * DW;
        atomicAdd(p + 0, a0); atomicAdd(p + 1, a1);
        atomicAdd(p + 2, a2); atomicAdd(p + 3, a3);
        atomicAdd(p + 4, a4); atomicAdd(p + 5, a5);
        atomicAdd(p + 6, a6); atomicAdd(p + 7, a7);
    }
#undef PROC
    __syncthreads();

    // writeback
    int rbase = b << 7;
    if (D == 128) {                            // bf16 out: 128 rows x 64 dims (half)
        for (int i = t; i < 1024; i += 256) {  // 8 uint4 per row
            int row = i >> 3, c = i & 7;
            int r = rbase + row;
            if (r < N_NODES) {
                const float* a = acc + row * DW + c * 8;
                float f0 = a[0], f1 = a[1], f2 = a[2], f3 = a[3];
                float f4 = a[4], f5 = a[5], f6 = a[6], f7 = a[7];
                if (RELU) {
                    f0 = fmaxf(f0, 0.f); f1 = fmaxf(f1, 0.f);
                    f2 = fmaxf(f2, 0.f); f3 = fmaxf(f3, 0.f);
                    f4 = fmaxf(f4, 0.f); f5 = fmaxf(f5, 0.f);
                    f6 = fmaxf(f6, 0.f); f7 = fmaxf(f7, 0.f);
                }
                uint4 o;
                o.x = (uint)f2bf(f0) | ((uint)f2bf(f1) << 16);
                o.y = (uint)f2bf(f2) | ((uint)f2bf(f3) << 16);
                o.z = (uint)f2bf(f4) | ((uint)f2bf(f5) << 16);
                o.w = (uint)f2bf(f6) | ((uint)f2bf(f7) << 16);
                ((uint4*)y)[(size_t)r * 16 + half * 8 + c] = o;
            }
        }
    } else {                                   // fp32 out: 128 rows x 64 dims
        for (int i = t; i < 2048; i += 256) {  // 16 float4 per row
            int row = i >> 4, c = i & 15;
            int r = rbase + row;
            if (r < N_NODES) {
                float4 o = ((float4*)acc)[row * 16 + c];
                if (RELU) {
                    o.x = fmaxf(o.x, 0.f); o.y = fmaxf(o.y, 0.f);
                    o.z = fmaxf(o.z, 0.f); o.w = fmaxf(o.w, 0.f);
                }
                ((float4*)y)[(size_t)r * 16 + c] = o;
            }
        }
    }
}

// ---------------- launch ----------------

extern "C" void kernel_launch(void* const* d_in, const int* in_sizes, int n_in,
                              void* d_out, int out_size, void* d_ws, size_t ws_size,
                              hipStream_t stream) {
    const float* x    = (const float*)d_in[0];
    const float* vals = (const float*)d_in[1];
    const float* W1   = (const float*)d_in[2];
    const float* b1   = (const float*)d_in[3];
    const float* W2   = (const float*)d_in[4];
    const float* b2   = (const float*)d_in[5];
    const float* W3   = (const float*)d_in[6];
    const float* b3   = (const float*)d_in[7];
    const int* row    = (const int*)d_in[8];
    const int* col    = (const int*)d_in[9];
    float* out = (float*)d_out;

    char* ws = (char*)d_ws;
    int2*   ep     = (int2*)  (ws + 0);          // 12,800,000
    int*    rowptr = (int*)   (ws + 12800000);   // 400,004
    int*    gcount = (int*)   (ws + 13250000);   // 3,128
    int*    bstart = (int*)   (ws + 13260000);   // 3,132 (NBK+1)
    ushort* Wt1    = (ushort*)(ws + 13601024);   // 32,768
    ushort* Wt2    = (ushort*)(ws + 13633792);   // 32,768
    ushort* Wt3    = (ushort*)(ws + 13666560);   // 16,384
    int*    offT   = (int*)   (ws + 13700096);   // (NBK+1)*NBA*4 = 613,872 (ends <14.4MB)
    ushort* g64    = (ushort*)(ws + 16000000);   // 12,800,000 (layer-3 gemm out)
    ushort* g      = (ushort*)(ws + 41600000);   // 25,600,000
    ushort* sbuf   = (ushort*)(ws + 67200000);   // 25,600,000  (total 92.8MB)

    // tmp aliases g (dead until gemm L1 writes it; build completes first).
    int2* tmp = (int2*)g;                        // NBA*EPB*8 = 12,845,056 <= 25.6MB

    // CSR build (counting sort by 128-row bucket)
    hipMemsetAsync(gcount, 0, NBK * sizeof(int), stream);
    hipLaunchKernelGGL(binA_k, dim3(NBA), dim3(1024), 0, stream,
                       row, col, vals, tmp, gcount, offT);
    hipLaunchKernelGGL(bscan_k, dim3(1), dim3(1024), 0, stream, gcount, bstart, rowptr);
    hipLaunchKernelGGL(binB_k, dim3(NBK), dim3(256), 0, stream,
                       tmp, offT, bstart, rowptr, ep);

    // weight converts
    hipLaunchKernelGGL(wcvt_k, dim3(64), dim3(256), 0, stream, W1, W2, W3, Wt1, Wt2, Wt3);

    const int GEMM_GRID = (N_NODES + 63) / 64;   // 1563

    // layer 1 (gemm reads fp32 x directly, converts in-register)
    hipLaunchKernelGGL((gemm_k<128, true>), dim3(GEMM_GRID), dim3(256), 0, stream, x, Wt1, b1, g);
    hipLaunchKernelGGL((spmm2_k<128, true>), dim3(2 * NBK), dim3(256), 0, stream,
                       bstart, ep, g, sbuf);
    // layer 2
    hipLaunchKernelGGL((gemm_k<128, false>), dim3(GEMM_GRID), dim3(256), 0, stream, sbuf, Wt2, b2, g);
    hipLaunchKernelGGL((spmm2_k<128, true>), dim3(2 * NBK), dim3(256), 0, stream,
                       bstart, ep, g, sbuf);
    // layer 3
    hipLaunchKernelGGL((gemm_k<64, false>), dim3(GEMM_GRID), dim3(256), 0, stream, sbuf, Wt3, b3, g64);
    hipLaunchKernelGGL((spmm2_k<64, false>), dim3(NBK), dim3(256), 0, stream,
                       bstart, ep, g64, out);
}

// Round 7
// 339.333 us; speedup vs baseline: 1.2313x; 1.2313x over previous
//
#include <hip/hip_runtime.h>

#define N_NODES 100000
#define N_EDGES 1600000

#define NBK 782    // row buckets of 128 rows: ceil(100000/128)
#define EPB 8192   // edges per binA block
#define NBA 196    // binA blocks: 196*8192 = 1,605,632 >= N_EDGES
#define CAPE 4096  // LDS edge-stage capacity in binB (mean bucket = 2046)

typedef __attribute__((ext_vector_type(8))) short short8;
typedef __attribute__((ext_vector_type(4))) float f32x4;

__device__ __forceinline__ ushort f2bf(float f) {
    uint u = __float_as_uint(f);
    return (ushort)((u + 0x7fff + ((u >> 16) & 1)) >> 16);   // RNE
}
__device__ __forceinline__ float bflo(uint p) { return __uint_as_float(p << 16); }
__device__ __forceinline__ float bfhi(uint p) { return __uint_as_float(p & 0xffff0000u); }

// ---------------- CSR build: two-pass counting sort by 128-row bucket ----------------

__global__ void __launch_bounds__(1024) binA_k(const int* __restrict__ row,
                                               const int* __restrict__ col,
                                               const float* __restrict__ vals,
                                               int2* __restrict__ tmp,
                                               int* __restrict__ gcount,
                                               int* __restrict__ offT) {
    __shared__ int h[NBK];
    __shared__ int cur[NBK];
    __shared__ int sh[1024];
    int t = threadIdx.x;
    int base = blockIdx.x * EPB;

    // stage 8 edges/thread in registers (row/col/vals each read exactly once)
    int rr[8], cc[8];
    float vv[8];
#pragma unroll
    for (int u = 0; u < 8; ++u) {
        int e = base + u * 1024 + t;
        bool ok = (e < N_EDGES);
        rr[u] = ok ? row[e] : -1;
        cc[u] = ok ? col[e] : 0;
        vv[u] = ok ? vals[e] : 0.f;
    }

    if (t < NBK) h[t] = 0;
    __syncthreads();
#pragma unroll
    for (int u = 0; u < 8; ++u)
        if (rr[u] >= 0) atomicAdd(&h[rr[u] >> 7], 1);
    __syncthreads();
    if (t < NBK && h[t]) atomicAdd(&gcount[t], h[t]);
    // exclusive scan of h over NBK (padded to 1024)
    sh[t] = (t < NBK) ? h[t] : 0;
    __syncthreads();
    for (int off = 1; off < 1024; off <<= 1) {
        int v = (t >= off) ? sh[t - off] : 0;
        __syncthreads();
        sh[t] += v;
        __syncthreads();
    }
    if (t < NBK) {
        int ex = t ? sh[t - 1] : 0;
        cur[t] = ex;
        offT[t * NBA + blockIdx.x] = ex;
    }
    if (t == NBK - 1) offT[NBK * NBA + blockIdx.x] = sh[t];  // row NBK = edges in block
    __syncthreads();
    // scatter into block-private region, grouped by bucket
#pragma unroll
    for (int u = 0; u < 8; ++u) {
        if (rr[u] >= 0) {
            int p = atomicAdd(&cur[rr[u] >> 7], 1);
            int2 v;
            v.x = ((rr[u] & 127) << 17) | cc[u];   // 7-bit row-in-bucket | 17-bit col
            v.y = __float_as_int(vv[u]);
            tmp[base + p] = v;
        }
    }
}

// exclusive scan of the 782 bucket totals -> bstart; also rowptr[N] = E
__global__ void __launch_bounds__(1024) bscan_k(const int* __restrict__ gcount,
                                                int* __restrict__ bstart,
                                                int* __restrict__ rowptr) {
    __shared__ int sh[1024];
    int t = threadIdx.x;
    sh[t] = (t < NBK) ? gcount[t] : 0;
    __syncthreads();
    for (int off = 1; off < 1024; off <<= 1) {
        int v = (t >= off) ? sh[t - off] : 0;
        __syncthreads();
        sh[t] += v;
        __syncthreads();
    }
    if (t < NBK) bstart[t] = t ? sh[t - 1] : 0;
    if (t == 0) rowptr[N_NODES] = N_EDGES;
}

// Phase B: one block per bucket; flat-index gather, LDS stage, scatter from LDS.
// Also emits a per-bucket DEGREE-SORTED worklist wl (ascending degree) so spmm waves
// co-schedule rows of similar degree (kills max-of-group divergence).

__global__ void __launch_bounds__(256) binB_k(const int2* __restrict__ tmp,
                                              const int* __restrict__ offT,
                                              const int* __restrict__ bstart,
                                              int* __restrict__ rowptr,
                                              int* __restrict__ wl,
                                              int2* __restrict__ ep) {
    __shared__ int goff[NBA];
    __shared__ int sstart[NBA];
    __shared__ int s_scan[256];
    __shared__ int h[128];
    __shared__ int cur[128];
    __shared__ int dcnt[64];
    __shared__ int dexc[64];
    __shared__ int2 ebuf[CAPE];
    __shared__ int sT;
    int b = blockIdx.x, t = threadIdx.x;

    int c = 0;
    if (t < NBA) {
        int o0 = offT[b * NBA + t];
        int o1 = offT[(b + 1) * NBA + t];
        c = o1 - o0;
        goff[t] = t * EPB + o0;
    }
    s_scan[t] = c;
    __syncthreads();
    for (int off = 1; off < 256; off <<= 1) {
        int v = (t >= off) ? s_scan[t - off] : 0;
        __syncthreads();
        s_scan[t] += v;
        __syncthreads();
    }
    if (t < NBA) sstart[t] = s_scan[t] - c;
    if (t == NBA - 1) sT = s_scan[t];
    if (t < 128) h[t] = 0;
    if (t < 64) dcnt[t] = 0;
    __syncthreads();
    int T = sT;

    // load + histogram + stage
    for (int j = t; j < T; j += 256) {
        int lo = 0, hi = NBA - 1;            // last s with sstart[s] <= j
        while (lo < hi) {
            int mid = (lo + hi + 1) >> 1;
            if (sstart[mid] <= j) lo = mid; else hi = mid - 1;
        }
        int2 v = tmp[goff[lo] + (j - sstart[lo])];
        atomicAdd(&h[v.x >> 17], 1);
        if (j < CAPE) ebuf[j] = v;
    }
    __syncthreads();
    int myc = (t < 128) ? h[t] : 0;          // this row's degree (pre-scan)
    // exclusive scan over 128 bins
    for (int off = 1; off < 128; off <<= 1) {
        int v = (t >= off && t < 128) ? h[t - off] : 0;
        __syncthreads();
        if (t < 128) h[t] += v;
        __syncthreads();
    }
    int bs = bstart[b];
    if (t < 128) {
        int ex = t ? h[t - 1] : 0;
        cur[t] = ex;
        int r = (b << 7) + t;
        if (r < N_NODES) rowptr[r] = bs + ex;
    }
    // degree-sorted worklist: counting sort over 64 degree bins (clamped)
    int bin = 0, rk = 0;
    if (t < 128) {
        bin = myc < 63 ? myc : 63;
        rk = atomicAdd(&dcnt[bin], 1);
    }
    __syncthreads();
    if (t == 0) {
        int acc2 = 0;
        for (int i2 = 0; i2 < 64; ++i2) { dexc[i2] = acc2; acc2 += dcnt[i2]; }
    }
    __syncthreads();
    if (t < 128) wl[(b << 7) + dexc[bin] + rk] = (b << 7) + t;
    // scatter to final CSR positions (from LDS; overflow re-reads global)
    for (int j = t; j < T; j += 256) {
        int2 v;
        if (j < CAPE) v = ebuf[j];
        else {
            int lo = 0, hi = NBA - 1;
            while (lo < hi) {
                int mid = (lo + hi + 1) >> 1;
                if (sstart[mid] <= j) lo = mid; else hi = mid - 1;
            }
            v = tmp[goff[lo] + (j - sstart[lo])];
        }
        int p = atomicAdd(&cur[v.x >> 17], 1);
        int2 w;
        w.x = v.x & 0x1ffff;
        w.y = v.y;
        ep[bs + p] = w;
    }
}

// ---------------- converts ----------------

// transpose-convert all three weight matrices: Wt[n][k] = bf16(W[k][n])
__global__ void wcvt_k(const float* __restrict__ W1, const float* __restrict__ W2,
                       const float* __restrict__ W3, ushort* __restrict__ Wt1,
                       ushort* __restrict__ Wt2, ushort* __restrict__ Wt3) {
    int i = blockIdx.x * 256 + threadIdx.x;
    if (i < 16384) {
        int n = i >> 7, k = i & 127;
        Wt1[i] = f2bf(W1[k * 128 + n]);
        Wt2[i] = f2bf(W2[k * 128 + n]);
    }
    if (i < 8192) {
        int n = i >> 7, k = i & 127;
        Wt3[i] = f2bf(W3[k * 64 + n]);
    }
}

// ---------------- GEMM: Y[r, 0..DN) = bf16( X[r,:] @ Wt^T + bias ) ----------------

template <int DN, bool AF32>
__global__ void __launch_bounds__(256) gemm_k(const void* __restrict__ Xa,
                                              const ushort* __restrict__ Wt,
                                              const float* __restrict__ bias,
                                              ushort* __restrict__ Y) {
    constexpr int NT = DN / 16;
    const ushort* Xb = (const ushort*)Xa;
    const float* Xf = (const float*)Xa;
    int wv = threadIdx.x >> 6;
    int l = threadIdx.x & 63;
    int lg = l >> 4, lm = l & 15;
    int rbase = blockIdx.x * 64 + wv * 16;

    int arow = rbase + lm;
    if (arow > N_NODES - 1) arow = N_NODES - 1;     // clamp (stores predicated)

    f32x4 acc[NT];
#pragma unroll
    for (int n = 0; n < NT; n++) acc[n] = (f32x4){0.f, 0.f, 0.f, 0.f};

#pragma unroll
    for (int kk = 0; kk < 4; ++kk) {
        short8 a;
        if constexpr (AF32) {
            const float* ap = Xf + (size_t)arow * 128 + kk * 32 + lg * 8;
            float4 u = *(const float4*)ap;
            float4 v = *(const float4*)(ap + 4);
            a = (short8){(short)f2bf(u.x), (short)f2bf(u.y), (short)f2bf(u.z), (short)f2bf(u.w),
                         (short)f2bf(v.x), (short)f2bf(v.y), (short)f2bf(v.z), (short)f2bf(v.w)};
        } else {
            a = *(const short8*)(Xb + (size_t)arow * 128 + kk * 32 + lg * 8);
        }
#pragma unroll
        for (int n = 0; n < NT; ++n) {
            short8 b = *(const short8*)(Wt + (size_t)(n * 16 + lm) * 128 + kk * 32 + lg * 8);
            acc[n] = __builtin_amdgcn_mfma_f32_16x16x32_bf16(a, b, acc[n], 0, 0, 0);
        }
    }

    int r0 = rbase + lg * 4;
#pragma unroll
    for (int n = 0; n < NT; ++n) {
        int c = n * 16 + lm;
        float bj = bias[c];
#pragma unroll
        for (int i = 0; i < 4; ++i) {
            int r = r0 + i;
            if (r < N_NODES) Y[(size_t)r * DN + c] = f2bf(acc[n][i] + bj);
        }
    }
}

// ---------------- SpMM (CSR; one lane-GROUP per row via degree-sorted worklist) ------
// D=128: 16-lane group per row (4 rows/wave). Lane hl holds dims [hl*8, hl*8+8) as
// uint4 (8 bf16). Rows come from wl (ascending degree) so a wave's rows have matching
// degree. Main loop stages 8 edges -> 8 gathers in flight per group. No shuffles.
// D=64:  8-lane group per row (8 rows/wave); fp32 2x float4 store.

#define FMA8(V, X) {                                                  \
    a0 = fmaf(V, bflo((X).x), a0); a1 = fmaf(V, bfhi((X).x), a1);     \
    a2 = fmaf(V, bflo((X).y), a2); a3 = fmaf(V, bfhi((X).y), a3);     \
    a4 = fmaf(V, bflo((X).z), a4); a5 = fmaf(V, bfhi((X).z), a5);     \
    a6 = fmaf(V, bflo((X).w), a6); a7 = fmaf(V, bfhi((X).w), a7); }

template <int D, bool RELU>
__global__ void __launch_bounds__(256) spmm_k(const int* __restrict__ rowptr,
                                              const int* __restrict__ wl,
                                              const int2* __restrict__ ep,
                                              const ushort* __restrict__ xb,
                                              void* __restrict__ y) {
    constexpr int LPG = (D == 128) ? 16 : 8;   // lanes per group (one row each)
    constexpr int RPB = 256 / LPG;             // rows per block
    int t = threadIdx.x;
    int g = t / LPG;
    int hl = t % LPG;
    int idx = blockIdx.x * RPB + g;
    if (idx >= NBK * 128) return;
    int w = wl[idx];
    if (w >= N_NODES) return;
    int s = rowptr[w], e = rowptr[w + 1];

    const uint4* xp = (const uint4*)xb;        // row stride LPG uint4
    float a0 = 0.f, a1 = 0.f, a2 = 0.f, a3 = 0.f;
    float a4 = 0.f, a5 = 0.f, a6 = 0.f, a7 = 0.f;

    int i = s;
    for (; i + 8 <= e; i += 8) {               // 8 gathers in flight per group
        int2 e0 = ep[i],     e1 = ep[i + 1], e2 = ep[i + 2], e3 = ep[i + 3];
        int2 e4 = ep[i + 4], e5 = ep[i + 5], e6 = ep[i + 6], e7 = ep[i + 7];
        uint4 x0 = xp[e0.x * LPG + hl];
        uint4 x1 = xp[e1.x * LPG + hl];
        uint4 x2 = xp[e2.x * LPG + hl];
        uint4 x3 = xp[e3.x * LPG + hl];
        uint4 x4 = xp[e4.x * LPG + hl];
        uint4 x5 = xp[e5.x * LPG + hl];
        uint4 x6 = xp[e6.x * LPG + hl];
        uint4 x7 = xp[e7.x * LPG + hl];
        FMA8(__int_as_float(e0.y), x0) FMA8(__int_as_float(e1.y), x1)
        FMA8(__int_as_float(e2.y), x2) FMA8(__int_as_float(e3.y), x3)
        FMA8(__int_as_float(e4.y), x4) FMA8(__int_as_float(e5.y), x5)
        FMA8(__int_as_float(e6.y), x6) FMA8(__int_as_float(e7.y), x7)
    }
    if (i + 4 <= e) {
        int2 e0 = ep[i], e1 = ep[i + 1], e2 = ep[i + 2], e3 = ep[i + 3];
        uint4 x0 = xp[e0.x * LPG + hl];
        uint4 x1 = xp[e1.x * LPG + hl];
        uint4 x2 = xp[e2.x * LPG + hl];
        uint4 x3 = xp[e3.x * LPG + hl];
        FMA8(__int_as_float(e0.y), x0) FMA8(__int_as_float(e1.y), x1)
        FMA8(__int_as_float(e2.y), x2) FMA8(__int_as_float(e3.y), x3)
        i += 4;
    }
    for (; i < e; ++i) {                       // tail (< 4 edges)
        int2 e0 = ep[i];
        uint4 x0 = xp[e0.x * LPG + hl];
        FMA8(__int_as_float(e0.y), x0)
    }
    if (RELU) {
        a0 = fmaxf(a0, 0.f); a1 = fmaxf(a1, 0.f); a2 = fmaxf(a2, 0.f); a3 = fmaxf(a3, 0.f);
        a4 = fmaxf(a4, 0.f); a5 = fmaxf(a5, 0.f); a6 = fmaxf(a6, 0.f); a7 = fmaxf(a7, 0.f);
    }
    if (D == 128) {                             // bf16 out
        uint4 o;
        o.x = (uint)f2bf(a0) | ((uint)f2bf(a1) << 16);
        o.y = (uint)f2bf(a2) | ((uint)f2bf(a3) << 16);
        o.z = (uint)f2bf(a4) | ((uint)f2bf(a5) << 16);
        o.w = (uint)f2bf(a6) | ((uint)f2bf(a7) << 16);
        ((uint4*)y)[w * 16 + hl] = o;
    } else {                                    // fp32 out: lane covers 8 floats
        float4 o0; o0.x = a0; o0.y = a1; o0.z = a2; o0.w = a3;
        float4 o1; o1.x = a4; o1.y = a5; o1.z = a6; o1.w = a7;
        ((float4*)y)[w * 16 + hl * 2] = o0;
        ((float4*)y)[w * 16 + hl * 2 + 1] = o1;
    }
}

// ---------------- launch ----------------

extern "C" void kernel_launch(void* const* d_in, const int* in_sizes, int n_in,
                              void* d_out, int out_size, void* d_ws, size_t ws_size,
                              hipStream_t stream) {
    const float* x    = (const float*)d_in[0];
    const float* vals = (const float*)d_in[1];
    const float* W1   = (const float*)d_in[2];
    const float* b1   = (const float*)d_in[3];
    const float* W2   = (const float*)d_in[4];
    const float* b2   = (const float*)d_in[5];
    const float* W3   = (const float*)d_in[6];
    const float* b3   = (const float*)d_in[7];
    const int* row    = (const int*)d_in[8];
    const int* col    = (const int*)d_in[9];
    float* out = (float*)d_out;

    char* ws = (char*)d_ws;
    int2*   ep     = (int2*)  (ws + 0);          // 12,800,000
    int*    rowptr = (int*)   (ws + 12800000);   // 400,004
    int*    gcount = (int*)   (ws + 13250000);   // 3,128
    int*    bstart = (int*)   (ws + 13260000);   // 3,132
    ushort* Wt1    = (ushort*)(ws + 13601024);   // 32,768
    ushort* Wt2    = (ushort*)(ws + 13633792);   // 32,768
    ushort* Wt3    = (ushort*)(ws + 13666560);   // 16,384
    int*    offT   = (int*)   (ws + 13700096);   // (NBK+1)*NBA*4 = 613,872
    int*    wl     = (int*)   (ws + 14400000);   // NBK*128*4 = 400,384 (ends <14.81MB)
    ushort* g64    = (ushort*)(ws + 16000000);   // 12,800,000 (layer-3 gemm out)
    ushort* g      = (ushort*)(ws + 41600000);   // 25,600,000
    ushort* sbuf   = (ushort*)(ws + 67200000);   // 25,600,000  (total 92.8MB)

    // tmp aliases g (dead until gemm L1 writes it; build completes first).
    int2* tmp = (int2*)g;                        // NBA*EPB*8 = 12,845,056 <= 25.6MB

    // CSR build (counting sort by 128-row bucket)
    hipMemsetAsync(gcount, 0, NBK * sizeof(int), stream);
    hipLaunchKernelGGL(binA_k, dim3(NBA), dim3(1024), 0, stream,
                       row, col, vals, tmp, gcount, offT);
    hipLaunchKernelGGL(bscan_k, dim3(1), dim3(1024), 0, stream, gcount, bstart, rowptr);
    hipLaunchKernelGGL(binB_k, dim3(NBK), dim3(256), 0, stream,
                       tmp, offT, bstart, rowptr, wl, ep);

    // weight converts
    hipLaunchKernelGGL(wcvt_k, dim3(64), dim3(256), 0, stream, W1, W2, W3, Wt1, Wt2, Wt3);

    const int GEMM_GRID = (N_NODES + 63) / 64;       // 1563
    const int SPMM_GRID_128 = NBK * 128 / 16;        // 6256
    const int SPMM_GRID_64  = NBK * 128 / 32;        // 3128

    // layer 1 (gemm reads fp32 x directly, converts in-register)
    hipLaunchKernelGGL((gemm_k<128, true>), dim3(GEMM_GRID), dim3(256), 0, stream, x, Wt1, b1, g);
    hipLaunchKernelGGL((spmm_k<128, true>), dim3(SPMM_GRID_128), dim3(256), 0, stream,
                       rowptr, wl, ep, g, sbuf);
    // layer 2
    hipLaunchKernelGGL((gemm_k<128, false>), dim3(GEMM_GRID), dim3(256), 0, stream, sbuf, Wt2, b2, g);
    hipLaunchKernelGGL((spmm_k<128, true>), dim3(SPMM_GRID_128), dim3(256), 0, stream,
                       rowptr, wl, ep, g, sbuf);
    // layer 3
    hipLaunchKernelGGL((gemm_k<64, false>), dim3(GEMM_GRID), dim3(256), 0, stream, sbuf, Wt3, b3, g64);
    hipLaunchKernelGGL((spmm_k<64, false>), dim3(SPMM_GRID_64), dim3(256), 0, stream,
                       rowptr, wl, ep, g64, out);
}

// Round 8
// 304.506 us; speedup vs baseline: 1.3721x; 1.1144x over previous
//
#include <hip/hip_runtime.h>

#define N_NODES 100000
#define N_EDGES 1600000

#define NBK 782    // row buckets of 128 rows: ceil(100000/128)
#define EPB 8192   // edges per binA block
#define NBA 196    // binA blocks: 196*8192 = 1,605,632 >= N_EDGES
#define CAPE 4096  // LDS edge-stage capacity in binB (mean bucket = 2047, sigma ~45)

typedef __attribute__((ext_vector_type(8))) short short8;
typedef __attribute__((ext_vector_type(4))) float f32x4;

__device__ __forceinline__ ushort f2bf(float f) {
    uint u = __float_as_uint(f);
    return (ushort)((u + 0x7fff + ((u >> 16) & 1)) >> 16);   // RNE
}
__device__ __forceinline__ float bflo(uint p) { return __uint_as_float(p << 16); }
__device__ __forceinline__ float bfhi(uint p) { return __uint_as_float(p & 0xffff0000u); }

// ---------------- CSR build: two-pass counting sort by 128-row bucket ----------------
// Phase A: block-private grouped write into tmp (1x write amplification); wave-shuffle
// scans (2 barriers instead of 20).

__global__ void __launch_bounds__(1024) binA_k(const int* __restrict__ row,
                                               const int* __restrict__ col,
                                               const float* __restrict__ vals,
                                               int2* __restrict__ tmp,
                                               int* __restrict__ gcount,
                                               int* __restrict__ offT) {
    __shared__ int h[NBK];
    __shared__ int cur[NBK];
    __shared__ int wpart[16];
    int t = threadIdx.x;
    int lane = t & 63;
    int base = blockIdx.x * EPB;

    // stage 8 edges/thread in registers (row/col/vals each read exactly once)
    int rr[8], cc[8];
    float vv[8];
#pragma unroll
    for (int u = 0; u < 8; ++u) {
        int e = base + u * 1024 + t;
        bool ok = (e < N_EDGES);
        rr[u] = ok ? row[e] : -1;
        cc[u] = ok ? col[e] : 0;
        vv[u] = ok ? vals[e] : 0.f;
    }

    if (t < NBK) h[t] = 0;
    __syncthreads();
#pragma unroll
    for (int u = 0; u < 8; ++u)
        if (rr[u] >= 0) atomicAdd(&h[rr[u] >> 7], 1);
    __syncthreads();
    int hv = (t < NBK) ? h[t] : 0;
    if (hv) atomicAdd(&gcount[t], hv);

    // wave-shuffle inclusive scan over thread order (h is zero past NBK)
    int v = hv;
    for (int off = 1; off < 64; off <<= 1) {
        int u2 = __shfl_up(v, off);
        if (lane >= off) v += u2;
    }
    if (lane == 63) wpart[t >> 6] = v;
    __syncthreads();
    if (t == 0) {
        int acc = 0;
#pragma unroll
        for (int i = 0; i < 16; ++i) { int w = wpart[i]; wpart[i] = acc; acc += w; }
    }
    __syncthreads();
    v += wpart[t >> 6];                      // inclusive prefix over h[0..t]
    if (t < NBK) {
        int ex = v - hv;
        cur[t] = ex;
        offT[t * NBA + blockIdx.x] = ex;
    }
    if (t == NBK - 1) offT[NBK * NBA + blockIdx.x] = v;  // row NBK = edges in block
    __syncthreads();
    // scatter into block-private region, grouped by bucket
#pragma unroll
    for (int u = 0; u < 8; ++u) {
        if (rr[u] >= 0) {
            int p = atomicAdd(&cur[rr[u] >> 7], 1);
            int2 w;
            w.x = ((rr[u] & 127) << 17) | cc[u];   // 7-bit row-in-bucket | 17-bit col
            w.y = __float_as_int(vv[u]);
            tmp[base + p] = w;
        }
    }
}

// exclusive scan of the 782 bucket totals -> bstart; also rowptr[N] = E
__global__ void __launch_bounds__(1024) bscan_k(const int* __restrict__ gcount,
                                                int* __restrict__ bstart,
                                                int* __restrict__ rowptr) {
    __shared__ int wpart[16];
    int t = threadIdx.x;
    int lane = t & 63;
    int g = (t < NBK) ? gcount[t] : 0;
    int v = g;
    for (int off = 1; off < 64; off <<= 1) {
        int u = __shfl_up(v, off);
        if (lane >= off) v += u;
    }
    if (lane == 63) wpart[t >> 6] = v;
    __syncthreads();
    if (t == 0) {
        int acc = 0;
#pragma unroll
        for (int i = 0; i < 16; ++i) { int w = wpart[i]; wpart[i] = acc; acc += w; }
    }
    __syncthreads();
    v += wpart[t >> 6];
    if (t < NBK) bstart[t] = v - g;
    if (t == 0) rowptr[N_NODES] = N_EDGES;
}

// Phase B: one block per bucket. NO binary search: a 16-lane group per segment loads
// the segment coalesced, histograms, and packs it into ebuf at its scanned dest;
// pass 2 scatters flat from the packed ebuf to final CSR positions.

__global__ void __launch_bounds__(256) binB_k(const int2* __restrict__ tmp,
                                              const int* __restrict__ offT,
                                              const int* __restrict__ bstart,
                                              int* __restrict__ rowptr,
                                              int2* __restrict__ ep) {
    __shared__ int goff[NBA];
    __shared__ int scnt[NBA];
    __shared__ int sdst[NBA];
    __shared__ int h[128];
    __shared__ int cur[128];
    __shared__ int2 ebuf[CAPE];
    __shared__ int wpart[4];
    __shared__ int hp;
    int b = blockIdx.x, t = threadIdx.x;
    int lane = t & 63;

    int c = 0;
    if (t < NBA) {
        int o0 = offT[b * NBA + t];
        int o1 = offT[(b + 1) * NBA + t];
        c = o1 - o0;
        goff[t] = t * EPB + o0;
        scnt[t] = c;
    }
    // exclusive scan of segment counts (wave shuffle, 256 threads)
    int v = c;
    for (int off = 1; off < 64; off <<= 1) {
        int u = __shfl_up(v, off);
        if (lane >= off) v += u;
    }
    if (lane == 63) wpart[t >> 6] = v;
    if (t < 128) h[t] = 0;
    __syncthreads();
    if (t == 0) {
        int acc = 0;
#pragma unroll
        for (int i = 0; i < 4; ++i) { int w = wpart[i]; wpart[i] = acc; acc += w; }
    }
    __syncthreads();
    v += wpart[t >> 6];
    if (t < NBA) sdst[t] = v - c;
    __syncthreads();

    // pass 1: 16-lane group per segment: coalesced load, LDS hist, pack into ebuf
    int grp = t >> 4, gl = t & 15;            // 16 groups of 16 lanes
    for (int s = grp; s < NBA; s += 16) {
        int n = scnt[s], go = goff[s], dd = sdst[s];
        for (int i = gl; i < n; i += 16) {
            int2 e = tmp[go + i];
            atomicAdd(&h[e.x >> 17], 1);
            ebuf[dd + i] = e;
        }
    }
    __syncthreads();
    // exclusive scan over 128 bins (2 waves + 1 partial)
    int hv = (t < 128) ? h[t] : 0;
    int sv = hv;
    for (int off = 1; off < 64; off <<= 1) {
        int u = __shfl_up(sv, off);
        if (lane >= off) sv += u;
    }
    if (t == 63) hp = sv;
    __syncthreads();
    int bs = bstart[b];
    if (t < 128) {
        int inc = sv + ((t >= 64) ? hp : 0);
        int ex = inc - hv;
        cur[t] = ex;
        int r = (b << 7) + t;
        if (r < N_NODES) rowptr[r] = bs + ex;
    }
    __syncthreads();
    // pass 2: flat scatter from packed ebuf to final CSR positions
    int T = sdst[NBA - 1] + scnt[NBA - 1];
    for (int j = t; j < T; j += 256) {
        int2 e = ebuf[j];
        int p = atomicAdd(&cur[e.x >> 17], 1);
        int2 w;
        w.x = e.x & 0x1ffff;
        w.y = e.y;
        ep[bs + p] = w;
    }
}

// ---------------- converts ----------------

// transpose-convert all three weight matrices: Wt[n][k] = bf16(W[k][n])
__global__ void wcvt_k(const float* __restrict__ W1, const float* __restrict__ W2,
                       const float* __restrict__ W3, ushort* __restrict__ Wt1,
                       ushort* __restrict__ Wt2, ushort* __restrict__ Wt3) {
    int i = blockIdx.x * 256 + threadIdx.x;
    if (i < 16384) {
        int n = i >> 7, k = i & 127;
        Wt1[i] = f2bf(W1[k * 128 + n]);
        Wt2[i] = f2bf(W2[k * 128 + n]);
    }
    if (i < 8192) {
        int n = i >> 7, k = i & 127;
        Wt3[i] = f2bf(W3[k * 64 + n]);
    }
}

// ---------------- GEMM: Y[r, 0..DN) = bf16( X[r,:] @ Wt^T + bias ) ----------------

template <int DN, bool AF32>
__global__ void __launch_bounds__(256) gemm_k(const void* __restrict__ Xa,
                                              const ushort* __restrict__ Wt,
                                              const float* __restrict__ bias,
                                              ushort* __restrict__ Y) {
    constexpr int NT = DN / 16;
    const ushort* Xb = (const ushort*)Xa;
    const float* Xf = (const float*)Xa;
    int wv = threadIdx.x >> 6;
    int l = threadIdx.x & 63;
    int lg = l >> 4, lm = l & 15;
    int rbase = blockIdx.x * 64 + wv * 16;

    int arow = rbase + lm;
    if (arow > N_NODES - 1) arow = N_NODES - 1;     // clamp (stores predicated)

    f32x4 acc[NT];
#pragma unroll
    for (int n = 0; n < NT; n++) acc[n] = (f32x4){0.f, 0.f, 0.f, 0.f};

#pragma unroll
    for (int kk = 0; kk < 4; ++kk) {
        short8 a;
        if constexpr (AF32) {
            const float* ap = Xf + (size_t)arow * 128 + kk * 32 + lg * 8;
            float4 u = *(const float4*)ap;
            float4 v = *(const float4*)(ap + 4);
            a = (short8){(short)f2bf(u.x), (short)f2bf(u.y), (short)f2bf(u.z), (short)f2bf(u.w),
                         (short)f2bf(v.x), (short)f2bf(v.y), (short)f2bf(v.z), (short)f2bf(v.w)};
        } else {
            a = *(const short8*)(Xb + (size_t)arow * 128 + kk * 32 + lg * 8);
        }
#pragma unroll
        for (int n = 0; n < NT; ++n) {
            short8 b = *(const short8*)(Wt + (size_t)(n * 16 + lm) * 128 + kk * 32 + lg * 8);
            acc[n] = __builtin_amdgcn_mfma_f32_16x16x32_bf16(a, b, acc[n], 0, 0, 0);
        }
    }

    int r0 = rbase + lg * 4;
#pragma unroll
    for (int n = 0; n < NT; ++n) {
        int c = n * 16 + lm;
        float bj = bias[c];
#pragma unroll
        for (int i = 0; i < 4; ++i) {
            int r = r0 + i;
            if (r < N_NODES) Y[(size_t)r * DN + c] = f2bf(acc[n][i] + bj);
        }
    }
}

// ---------------- SpMM (CSR; one lane-GROUP per row — proven round-5 form) ----------
// D=128: 16-lane group per row (4 rows/wave). Lane hl holds dims [hl*8, hl*8+8) as
// uint4 (8 bf16). Group walks its row's edges sequentially, 4 staged per iter.
// D=64:  8-lane group per row (8 rows/wave); fp32 2x float4 store.

template <int D, bool RELU>
__global__ void __launch_bounds__(256) spmm_k(const int* __restrict__ rowptr,
                                              const int2* __restrict__ ep,
                                              const ushort* __restrict__ xb,
                                              void* __restrict__ y) {
    constexpr int LPG = (D == 128) ? 16 : 8;   // lanes per group (one row each)
    constexpr int RPB = 256 / LPG;             // rows per block
    int t = threadIdx.x;
    int g = t / LPG;
    int hl = t % LPG;
    int w = blockIdx.x * RPB + g;
    if (w >= N_NODES) return;
    int s = rowptr[w], e = rowptr[w + 1];

    const uint4* xp = (const uint4*)xb;        // row stride LPG uint4
    float a0 = 0.f, a1 = 0.f, a2 = 0.f, a3 = 0.f;
    float a4 = 0.f, a5 = 0.f, a6 = 0.f, a7 = 0.f;

    int i = s;
    for (; i + 4 <= e; i += 4) {               // 4 edges staged -> 4 gathers in flight
        int2 e0 = ep[i], e1 = ep[i + 1], e2 = ep[i + 2], e3 = ep[i + 3];
        uint4 x0 = xp[e0.x * LPG + hl];
        uint4 x1 = xp[e1.x * LPG + hl];
        uint4 x2 = xp[e2.x * LPG + hl];
        uint4 x3 = xp[e3.x * LPG + hl];
        float v0 = __int_as_float(e0.y), v1 = __int_as_float(e1.y);
        float v2 = __int_as_float(e2.y), v3 = __int_as_float(e3.y);
        a0 = fmaf(v0, bflo(x0.x), a0); a1 = fmaf(v0, bfhi(x0.x), a1);
        a2 = fmaf(v0, bflo(x0.y), a2); a3 = fmaf(v0, bfhi(x0.y), a3);
        a4 = fmaf(v0, bflo(x0.z), a4); a5 = fmaf(v0, bfhi(x0.z), a5);
        a6 = fmaf(v0, bflo(x0.w), a6); a7 = fmaf(v0, bfhi(x0.w), a7);
        a0 = fmaf(v1, bflo(x1.x), a0); a1 = fmaf(v1, bfhi(x1.x), a1);
        a2 = fmaf(v1, bflo(x1.y), a2); a3 = fmaf(v1, bfhi(x1.y), a3);
        a4 = fmaf(v1, bflo(x1.z), a4); a5 = fmaf(v1, bfhi(x1.z), a5);
        a6 = fmaf(v1, bflo(x1.w), a6); a7 = fmaf(v1, bfhi(x1.w), a7);
        a0 = fmaf(v2, bflo(x2.x), a0); a1 = fmaf(v2, bfhi(x2.x), a1);
        a2 = fmaf(v2, bflo(x2.y), a2); a3 = fmaf(v2, bfhi(x2.y), a3);
        a4 = fmaf(v2, bflo(x2.z), a4); a5 = fmaf(v2, bfhi(x2.z), a5);
        a6 = fmaf(v2, bflo(x2.w), a6); a7 = fmaf(v2, bfhi(x2.w), a7);
        a0 = fmaf(v3, bflo(x3.x), a0); a1 = fmaf(v3, bfhi(x3.x), a1);
        a2 = fmaf(v3, bflo(x3.y), a2); a3 = fmaf(v3, bfhi(x3.y), a3);
        a4 = fmaf(v3, bflo(x3.z), a4); a5 = fmaf(v3, bfhi(x3.z), a5);
        a6 = fmaf(v3, bflo(x3.w), a6); a7 = fmaf(v3, bfhi(x3.w), a7);
    }
    for (; i < e; ++i) {                       // tail (< 4 edges)
        int2 e0 = ep[i];
        uint4 x0 = xp[e0.x * LPG + hl];
        float v0 = __int_as_float(e0.y);
        a0 = fmaf(v0, bflo(x0.x), a0); a1 = fmaf(v0, bfhi(x0.x), a1);
        a2 = fmaf(v0, bflo(x0.y), a2); a3 = fmaf(v0, bfhi(x0.y), a3);
        a4 = fmaf(v0, bflo(x0.z), a4); a5 = fmaf(v0, bfhi(x0.z), a5);
        a6 = fmaf(v0, bflo(x0.w), a6); a7 = fmaf(v0, bfhi(x0.w), a7);
    }
    if (RELU) {
        a0 = fmaxf(a0, 0.f); a1 = fmaxf(a1, 0.f); a2 = fmaxf(a2, 0.f); a3 = fmaxf(a3, 0.f);
        a4 = fmaxf(a4, 0.f); a5 = fmaxf(a5, 0.f); a6 = fmaxf(a6, 0.f); a7 = fmaxf(a7, 0.f);
    }
    if (D == 128) {                             // bf16 out
        uint4 o;
        o.x = (uint)f2bf(a0) | ((uint)f2bf(a1) << 16);
        o.y = (uint)f2bf(a2) | ((uint)f2bf(a3) << 16);
        o.z = (uint)f2bf(a4) | ((uint)f2bf(a5) << 16);
        o.w = (uint)f2bf(a6) | ((uint)f2bf(a7) << 16);
        ((uint4*)y)[w * 16 + hl] = o;
    } else {                                    // fp32 out: lane covers 8 floats
        float4 o0; o0.x = a0; o0.y = a1; o0.z = a2; o0.w = a3;
        float4 o1; o1.x = a4; o1.y = a5; o1.z = a6; o1.w = a7;
        ((float4*)y)[w * 16 + hl * 2] = o0;
        ((float4*)y)[w * 16 + hl * 2 + 1] = o1;
    }
}

// ---------------- launch ----------------

extern "C" void kernel_launch(void* const* d_in, const int* in_sizes, int n_in,
                              void* d_out, int out_size, void* d_ws, size_t ws_size,
                              hipStream_t stream) {
    const float* x    = (const float*)d_in[0];
    const float* vals = (const float*)d_in[1];
    const float* W1   = (const float*)d_in[2];
    const float* b1   = (const float*)d_in[3];
    const float* W2   = (const float*)d_in[4];
    const float* b2   = (const float*)d_in[5];
    const float* W3   = (const float*)d_in[6];
    const float* b3   = (const float*)d_in[7];
    const int* row    = (const int*)d_in[8];
    const int* col    = (const int*)d_in[9];
    float* out = (float*)d_out;

    char* ws = (char*)d_ws;
    int2*   ep     = (int2*)  (ws + 0);          // 12,800,000
    int*    rowptr = (int*)   (ws + 12800000);   // 400,004
    int*    gcount = (int*)   (ws + 13250000);   // 3,128
    int*    bstart = (int*)   (ws + 13260000);   // 3,128
    ushort* Wt1    = (ushort*)(ws + 13601024);   // 32,768
    ushort* Wt2    = (ushort*)(ws + 13633792);   // 32,768
    ushort* Wt3    = (ushort*)(ws + 13666560);   // 16,384
    int*    offT   = (int*)   (ws + 13700096);   // (NBK+1)*NBA*4 = 613,872
    ushort* g64    = (ushort*)(ws + 16000000);   // 12,800,000 (layer-3 gemm out)
    ushort* g      = (ushort*)(ws + 41600000);   // 25,600,000
    ushort* sbuf   = (ushort*)(ws + 67200000);   // 25,600,000  (total 92.8MB)

    // tmp aliases g (dead until gemm L1 writes it; build completes first).
    int2* tmp = (int2*)g;                        // NBA*EPB*8 = 12,845,056 <= 25.6MB

    // CSR build (counting sort by 128-row bucket)
    hipMemsetAsync(gcount, 0, NBK * sizeof(int), stream);
    hipLaunchKernelGGL(binA_k, dim3(NBA), dim3(1024), 0, stream,
                       row, col, vals, tmp, gcount, offT);
    hipLaunchKernelGGL(bscan_k, dim3(1), dim3(1024), 0, stream, gcount, bstart, rowptr);
    hipLaunchKernelGGL(binB_k, dim3(NBK), dim3(256), 0, stream,
                       tmp, offT, bstart, rowptr, ep);

    // weight converts
    hipLaunchKernelGGL(wcvt_k, dim3(64), dim3(256), 0, stream, W1, W2, W3, Wt1, Wt2, Wt3);

    const int GEMM_GRID = (N_NODES + 63) / 64;     // 1563
    const int SPMM_GRID_128 = (N_NODES + 15) / 16; // 6250
    const int SPMM_GRID_64  = (N_NODES + 31) / 32; // 3125

    // layer 1 (gemm reads fp32 x directly, converts in-register)
    hipLaunchKernelGGL((gemm_k<128, true>), dim3(GEMM_GRID), dim3(256), 0, stream, x, Wt1, b1, g);
    hipLaunchKernelGGL((spmm_k<128, true>), dim3(SPMM_GRID_128), dim3(256), 0, stream,
                       rowptr, ep, g, sbuf);
    // layer 2
    hipLaunchKernelGGL((gemm_k<128, false>), dim3(GEMM_GRID), dim3(256), 0, stream, sbuf, Wt2, b2, g);
    hipLaunchKernelGGL((spmm_k<128, true>), dim3(SPMM_GRID_128), dim3(256), 0, stream,
                       rowptr, ep, g, sbuf);
    // layer 3
    hipLaunchKernelGGL((gemm_k<64, false>), dim3(GEMM_GRID), dim3(256), 0, stream, sbuf, Wt3, b3, g64);
    hipLaunchKernelGGL((spmm_k<64, false>), dim3(SPMM_GRID_64), dim3(256), 0, stream,
                       rowptr, ep, g64, out);
}

// Round 9
// 301.913 us; speedup vs baseline: 1.3839x; 1.0086x over previous
//
#include <hip/hip_runtime.h>

#define N_NODES 100000
#define N_EDGES 1600000

#define NBK 782    // row buckets of 128 rows: ceil(100000/128)
#define EPB 8192   // edges per binA block
#define NBA 196    // binA blocks: 196*8192 = 1,605,632 >= N_EDGES
#define CAPE 4096  // LDS edge-stage capacity in binB (mean bucket = 2047, sigma ~45)

typedef __attribute__((ext_vector_type(8))) short short8;
typedef __attribute__((ext_vector_type(4))) float f32x4;

__device__ __forceinline__ ushort f2bf(float f) {
    uint u = __float_as_uint(f);
    return (ushort)((u + 0x7fff + ((u >> 16) & 1)) >> 16);   // RNE
}
__device__ __forceinline__ float bflo(uint p) { return __uint_as_float(p << 16); }
__device__ __forceinline__ float bfhi(uint p) { return __uint_as_float(p & 0xffff0000u); }

// ---------------- CSR build: two-pass counting sort by 128-row bucket ----------------
// Phase A: block-private grouped write into tmp (1x write amplification); wave-shuffle
// scans (2 barriers instead of 20).

__global__ void __launch_bounds__(1024) binA_k(const int* __restrict__ row,
                                               const int* __restrict__ col,
                                               const float* __restrict__ vals,
                                               int2* __restrict__ tmp,
                                               int* __restrict__ gcount,
                                               int* __restrict__ offT) {
    __shared__ int h[NBK];
    __shared__ int cur[NBK];
    __shared__ int wpart[16];
    int t = threadIdx.x;
    int lane = t & 63;
    int base = blockIdx.x * EPB;

    // stage 8 edges/thread in registers (row/col/vals each read exactly once)
    int rr[8], cc[8];
    float vv[8];
#pragma unroll
    for (int u = 0; u < 8; ++u) {
        int e = base + u * 1024 + t;
        bool ok = (e < N_EDGES);
        rr[u] = ok ? row[e] : -1;
        cc[u] = ok ? col[e] : 0;
        vv[u] = ok ? vals[e] : 0.f;
    }

    if (t < NBK) h[t] = 0;
    __syncthreads();
#pragma unroll
    for (int u = 0; u < 8; ++u)
        if (rr[u] >= 0) atomicAdd(&h[rr[u] >> 7], 1);
    __syncthreads();
    int hv = (t < NBK) ? h[t] : 0;
    if (hv) atomicAdd(&gcount[t], hv);

    // wave-shuffle inclusive scan over thread order (h is zero past NBK)
    int v = hv;
    for (int off = 1; off < 64; off <<= 1) {
        int u2 = __shfl_up(v, off);
        if (lane >= off) v += u2;
    }
    if (lane == 63) wpart[t >> 6] = v;
    __syncthreads();
    if (t == 0) {
        int acc = 0;
#pragma unroll
        for (int i = 0; i < 16; ++i) { int w = wpart[i]; wpart[i] = acc; acc += w; }
    }
    __syncthreads();
    v += wpart[t >> 6];                      // inclusive prefix over h[0..t]
    if (t < NBK) {
        int ex = v - hv;
        cur[t] = ex;
        offT[t * NBA + blockIdx.x] = ex;
    }
    if (t == NBK - 1) offT[NBK * NBA + blockIdx.x] = v;  // row NBK = edges in block
    __syncthreads();
    // scatter into block-private region, grouped by bucket
#pragma unroll
    for (int u = 0; u < 8; ++u) {
        if (rr[u] >= 0) {
            int p = atomicAdd(&cur[rr[u] >> 7], 1);
            int2 w;
            w.x = ((rr[u] & 127) << 17) | cc[u];   // 7-bit row-in-bucket | 17-bit col
            w.y = __float_as_int(vv[u]);
            tmp[base + p] = w;
        }
    }
}

// exclusive scan of the 782 bucket totals -> bstart; also rowptr[N] = E
__global__ void __launch_bounds__(1024) bscan_k(const int* __restrict__ gcount,
                                                int* __restrict__ bstart,
                                                int* __restrict__ rowptr) {
    __shared__ int wpart[16];
    int t = threadIdx.x;
    int lane = t & 63;
    int g = (t < NBK) ? gcount[t] : 0;
    int v = g;
    for (int off = 1; off < 64; off <<= 1) {
        int u = __shfl_up(v, off);
        if (lane >= off) v += u;
    }
    if (lane == 63) wpart[t >> 6] = v;
    __syncthreads();
    if (t == 0) {
        int acc = 0;
#pragma unroll
        for (int i = 0; i < 16; ++i) { int w = wpart[i]; wpart[i] = acc; acc += w; }
    }
    __syncthreads();
    v += wpart[t >> 6];
    if (t < NBK) bstart[t] = v - g;
    if (t == 0) rowptr[N_NODES] = N_EDGES;
}

// Phase B: one block per bucket. NO binary search: a 16-lane group per segment loads
// the segment coalesced, histograms, and packs it into ebuf at its scanned dest;
// pass 2 scatters flat from the packed ebuf to final CSR positions.

__global__ void __launch_bounds__(256) binB_k(const int2* __restrict__ tmp,
                                              const int* __restrict__ offT,
                                              const int* __restrict__ bstart,
                                              int* __restrict__ rowptr,
                                              int2* __restrict__ ep) {
    __shared__ int goff[NBA];
    __shared__ int scnt[NBA];
    __shared__ int sdst[NBA];
    __shared__ int h[128];
    __shared__ int cur[128];
    __shared__ int2 ebuf[CAPE];
    __shared__ int wpart[4];
    __shared__ int hp;
    int b = blockIdx.x, t = threadIdx.x;
    int lane = t & 63;

    int c = 0;
    if (t < NBA) {
        int o0 = offT[b * NBA + t];
        int o1 = offT[(b + 1) * NBA + t];
        c = o1 - o0;
        goff[t] = t * EPB + o0;
        scnt[t] = c;
    }
    // exclusive scan of segment counts (wave shuffle, 256 threads)
    int v = c;
    for (int off = 1; off < 64; off <<= 1) {
        int u = __shfl_up(v, off);
        if (lane >= off) v += u;
    }
    if (lane == 63) wpart[t >> 6] = v;
    if (t < 128) h[t] = 0;
    __syncthreads();
    if (t == 0) {
        int acc = 0;
#pragma unroll
        for (int i = 0; i < 4; ++i) { int w = wpart[i]; wpart[i] = acc; acc += w; }
    }
    __syncthreads();
    v += wpart[t >> 6];
    if (t < NBA) sdst[t] = v - c;
    __syncthreads();

    // pass 1: 16-lane group per segment: coalesced load, LDS hist, pack into ebuf
    int grp = t >> 4, gl = t & 15;            // 16 groups of 16 lanes
    for (int s = grp; s < NBA; s += 16) {
        int n = scnt[s], go = goff[s], dd = sdst[s];
        for (int i = gl; i < n; i += 16) {
            int2 e = tmp[go + i];
            atomicAdd(&h[e.x >> 17], 1);
            ebuf[dd + i] = e;
        }
    }
    __syncthreads();
    // exclusive scan over 128 bins (2 waves + 1 partial)
    int hv = (t < 128) ? h[t] : 0;
    int sv = hv;
    for (int off = 1; off < 64; off <<= 1) {
        int u = __shfl_up(sv, off);
        if (lane >= off) sv += u;
    }
    if (t == 63) hp = sv;
    __syncthreads();
    int bs = bstart[b];
    if (t < 128) {
        int inc = sv + ((t >= 64) ? hp : 0);
        int ex = inc - hv;
        cur[t] = ex;
        int r = (b << 7) + t;
        if (r < N_NODES) rowptr[r] = bs + ex;
    }
    __syncthreads();
    // pass 2: flat scatter from packed ebuf to final CSR positions
    int T = sdst[NBA - 1] + scnt[NBA - 1];
    for (int j = t; j < T; j += 256) {
        int2 e = ebuf[j];
        int p = atomicAdd(&cur[e.x >> 17], 1);
        int2 w;
        w.x = e.x & 0x1ffff;
        w.y = e.y;
        ep[bs + p] = w;
    }
}

// ---------------- converts ----------------

// transpose-convert all three weight matrices: Wt[n][k] = bf16(W[k][n]).
// Also zeroes gcount (this kernel launches FIRST, replacing the memset dispatch).
__global__ void wcvt_k(const float* __restrict__ W1, const float* __restrict__ W2,
                       const float* __restrict__ W3, ushort* __restrict__ Wt1,
                       ushort* __restrict__ Wt2, ushort* __restrict__ Wt3,
                       int* __restrict__ gcount) {
    int i = blockIdx.x * 256 + threadIdx.x;
    if (i < NBK) gcount[i] = 0;
    if (i < 16384) {
        int n = i >> 7, k = i & 127;
        Wt1[i] = f2bf(W1[k * 128 + n]);
        Wt2[i] = f2bf(W2[k * 128 + n]);
    }
    if (i < 8192) {
        int n = i >> 7, k = i & 127;
        Wt3[i] = f2bf(W3[k * 64 + n]);
    }
}

// ---------------- GEMM: Y[r, 0..DN) = bf16( X[r,:] @ Wt^T + bias ) ----------------

template <int DN, bool AF32>
__global__ void __launch_bounds__(256) gemm_k(const void* __restrict__ Xa,
                                              const ushort* __restrict__ Wt,
                                              const float* __restrict__ bias,
                                              ushort* __restrict__ Y) {
    constexpr int NT = DN / 16;
    const ushort* Xb = (const ushort*)Xa;
    const float* Xf = (const float*)Xa;
    int wv = threadIdx.x >> 6;
    int l = threadIdx.x & 63;
    int lg = l >> 4, lm = l & 15;
    int rbase = blockIdx.x * 64 + wv * 16;

    int arow = rbase + lm;
    if (arow > N_NODES - 1) arow = N_NODES - 1;     // clamp (stores predicated)

    f32x4 acc[NT];
#pragma unroll
    for (int n = 0; n < NT; n++) acc[n] = (f32x4){0.f, 0.f, 0.f, 0.f};

#pragma unroll
    for (int kk = 0; kk < 4; ++kk) {
        short8 a;
        if constexpr (AF32) {
            const float* ap = Xf + (size_t)arow * 128 + kk * 32 + lg * 8;
            float4 u = *(const float4*)ap;
            float4 v = *(const float4*)(ap + 4);
            a = (short8){(short)f2bf(u.x), (short)f2bf(u.y), (short)f2bf(u.z), (short)f2bf(u.w),
                         (short)f2bf(v.x), (short)f2bf(v.y), (short)f2bf(v.z), (short)f2bf(v.w)};
        } else {
            a = *(const short8*)(Xb + (size_t)arow * 128 + kk * 32 + lg * 8);
        }
#pragma unroll
        for (int n = 0; n < NT; ++n) {
            short8 b = *(const short8*)(Wt + (size_t)(n * 16 + lm) * 128 + kk * 32 + lg * 8);
            acc[n] = __builtin_amdgcn_mfma_f32_16x16x32_bf16(a, b, acc[n], 0, 0, 0);
        }
    }

    int r0 = rbase + lg * 4;
#pragma unroll
    for (int n = 0; n < NT; ++n) {
        int c = n * 16 + lm;
        float bj = bias[c];
#pragma unroll
        for (int i = 0; i < 4; ++i) {
            int r = r0 + i;
            if (r < N_NODES) Y[(size_t)r * DN + c] = f2bf(acc[n][i] + bj);
        }
    }
}

// ---------------- SpMM (CSR; one 16-lane group per row) ------------------------------
// D=128: lane hl holds dims [hl*8, hl*8+8) as uint4 (8 bf16); 4 rows/wave.
// D=64:  lane hl holds dims [hl*4, hl*4+4) as uint2 (4 bf16); 4 rows/wave (same
//        divergence width and block count as D=128; fp32 float4 store).

template <int D, bool RELU>
__global__ void __launch_bounds__(256) spmm_k(const int* __restrict__ rowptr,
                                              const int2* __restrict__ ep,
                                              const ushort* __restrict__ xb,
                                              void* __restrict__ y) {
    constexpr int LPG = 16;                    // lanes per group (one row each)
    constexpr int RPB = 256 / LPG;             // rows per block = 16
    int t = threadIdx.x;
    int g = t / LPG;
    int hl = t % LPG;
    int w = blockIdx.x * RPB + g;
    if (w >= N_NODES) return;
    int s = rowptr[w], e = rowptr[w + 1];

    if (D == 128) {
        const uint4* xp = (const uint4*)xb;    // row stride 16 uint4
        float a0 = 0.f, a1 = 0.f, a2 = 0.f, a3 = 0.f;
        float a4 = 0.f, a5 = 0.f, a6 = 0.f, a7 = 0.f;
        int i = s;
        for (; i + 4 <= e; i += 4) {           // 4 gathers in flight per group
            int2 e0 = ep[i], e1 = ep[i + 1], e2 = ep[i + 2], e3 = ep[i + 3];
            uint4 x0 = xp[e0.x * 16 + hl];
            uint4 x1 = xp[e1.x * 16 + hl];
            uint4 x2 = xp[e2.x * 16 + hl];
            uint4 x3 = xp[e3.x * 16 + hl];
            float v0 = __int_as_float(e0.y), v1 = __int_as_float(e1.y);
            float v2 = __int_as_float(e2.y), v3 = __int_as_float(e3.y);
            a0 = fmaf(v0, bflo(x0.x), a0); a1 = fmaf(v0, bfhi(x0.x), a1);
            a2 = fmaf(v0, bflo(x0.y), a2); a3 = fmaf(v0, bfhi(x0.y), a3);
            a4 = fmaf(v0, bflo(x0.z), a4); a5 = fmaf(v0, bfhi(x0.z), a5);
            a6 = fmaf(v0, bflo(x0.w), a6); a7 = fmaf(v0, bfhi(x0.w), a7);
            a0 = fmaf(v1, bflo(x1.x), a0); a1 = fmaf(v1, bfhi(x1.x), a1);
            a2 = fmaf(v1, bflo(x1.y), a2); a3 = fmaf(v1, bfhi(x1.y), a3);
            a4 = fmaf(v1, bflo(x1.z), a4); a5 = fmaf(v1, bfhi(x1.z), a5);
            a6 = fmaf(v1, bflo(x1.w), a6); a7 = fmaf(v1, bfhi(x1.w), a7);
            a0 = fmaf(v2, bflo(x2.x), a0); a1 = fmaf(v2, bfhi(x2.x), a1);
            a2 = fmaf(v2, bflo(x2.y), a2); a3 = fmaf(v2, bfhi(x2.y), a3);
            a4 = fmaf(v2, bflo(x2.z), a4); a5 = fmaf(v2, bfhi(x2.z), a5);
            a6 = fmaf(v2, bflo(x2.w), a6); a7 = fmaf(v2, bfhi(x2.w), a7);
            a0 = fmaf(v3, bflo(x3.x), a0); a1 = fmaf(v3, bfhi(x3.x), a1);
            a2 = fmaf(v3, bflo(x3.y), a2); a3 = fmaf(v3, bfhi(x3.y), a3);
            a4 = fmaf(v3, bflo(x3.z), a4); a5 = fmaf(v3, bfhi(x3.z), a5);
            a6 = fmaf(v3, bflo(x3.w), a6); a7 = fmaf(v3, bfhi(x3.w), a7);
        }
        for (; i < e; ++i) {
            int2 e0 = ep[i];
            uint4 x0 = xp[e0.x * 16 + hl];
            float v0 = __int_as_float(e0.y);
            a0 = fmaf(v0, bflo(x0.x), a0); a1 = fmaf(v0, bfhi(x0.x), a1);
            a2 = fmaf(v0, bflo(x0.y), a2); a3 = fmaf(v0, bfhi(x0.y), a3);
            a4 = fmaf(v0, bflo(x0.z), a4); a5 = fmaf(v0, bfhi(x0.z), a5);
            a6 = fmaf(v0, bflo(x0.w), a6); a7 = fmaf(v0, bfhi(x0.w), a7);
        }
        if (RELU) {
            a0 = fmaxf(a0, 0.f); a1 = fmaxf(a1, 0.f); a2 = fmaxf(a2, 0.f); a3 = fmaxf(a3, 0.f);
            a4 = fmaxf(a4, 0.f); a5 = fmaxf(a5, 0.f); a6 = fmaxf(a6, 0.f); a7 = fmaxf(a7, 0.f);
        }
        uint4 o;
        o.x = (uint)f2bf(a0) | ((uint)f2bf(a1) << 16);
        o.y = (uint)f2bf(a2) | ((uint)f2bf(a3) << 16);
        o.z = (uint)f2bf(a4) | ((uint)f2bf(a5) << 16);
        o.w = (uint)f2bf(a6) | ((uint)f2bf(a7) << 16);
        ((uint4*)y)[w * 16 + hl] = o;
    } else {  // D == 64
        const uint2* xp = (const uint2*)xb;    // row stride 16 uint2
        float a0 = 0.f, a1 = 0.f, a2 = 0.f, a3 = 0.f;
        int i = s;
        for (; i + 4 <= e; i += 4) {
            int2 e0 = ep[i], e1 = ep[i + 1], e2 = ep[i + 2], e3 = ep[i + 3];
            uint2 x0 = xp[e0.x * 16 + hl];
            uint2 x1 = xp[e1.x * 16 + hl];
            uint2 x2 = xp[e2.x * 16 + hl];
            uint2 x3 = xp[e3.x * 16 + hl];
            float v0 = __int_as_float(e0.y), v1 = __int_as_float(e1.y);
            float v2 = __int_as_float(e2.y), v3 = __int_as_float(e3.y);
            a0 = fmaf(v0, bflo(x0.x), a0); a1 = fmaf(v0, bfhi(x0.x), a1);
            a2 = fmaf(v0, bflo(x0.y), a2); a3 = fmaf(v0, bfhi(x0.y), a3);
            a0 = fmaf(v1, bflo(x1.x), a0); a1 = fmaf(v1, bfhi(x1.x), a1);
            a2 = fmaf(v1, bflo(x1.y), a2); a3 = fmaf(v1, bfhi(x1.y), a3);
            a0 = fmaf(v2, bflo(x2.x), a0); a1 = fmaf(v2, bfhi(x2.x), a1);
            a2 = fmaf(v2, bflo(x2.y), a2); a3 = fmaf(v2, bfhi(x2.y), a3);
            a0 = fmaf(v3, bflo(x3.x), a0); a1 = fmaf(v3, bfhi(x3.x), a1);
            a2 = fmaf(v3, bflo(x3.y), a2); a3 = fmaf(v3, bfhi(x3.y), a3);
        }
        for (; i < e; ++i) {
            int2 e0 = ep[i];
            uint2 x0 = xp[e0.x * 16 + hl];
            float v0 = __int_as_float(e0.y);
            a0 = fmaf(v0, bflo(x0.x), a0); a1 = fmaf(v0, bfhi(x0.x), a1);
            a2 = fmaf(v0, bflo(x0.y), a2); a3 = fmaf(v0, bfhi(x0.y), a3);
        }
        if (RELU) {
            a0 = fmaxf(a0, 0.f); a1 = fmaxf(a1, 0.f);
            a2 = fmaxf(a2, 0.f); a3 = fmaxf(a3, 0.f);
        }
        float4 o; o.x = a0; o.y = a1; o.z = a2; o.w = a3;
        ((float4*)y)[w * 16 + hl] = o;          // final output fp32
    }
}

// ---------------- launch ----------------

extern "C" void kernel_launch(void* const* d_in, const int* in_sizes, int n_in,
                              void* d_out, int out_size, void* d_ws, size_t ws_size,
                              hipStream_t stream) {
    const float* x    = (const float*)d_in[0];
    const float* vals = (const float*)d_in[1];
    const float* W1   = (const float*)d_in[2];
    const float* b1   = (const float*)d_in[3];
    const float* W2   = (const float*)d_in[4];
    const float* b2   = (const float*)d_in[5];
    const float* W3   = (const float*)d_in[6];
    const float* b3   = (const float*)d_in[7];
    const int* row    = (const int*)d_in[8];
    const int* col    = (const int*)d_in[9];
    float* out = (float*)d_out;

    char* ws = (char*)d_ws;
    int2*   ep     = (int2*)  (ws + 0);          // 12,800,000
    int*    rowptr = (int*)   (ws + 12800000);   // 400,004
    int*    gcount = (int*)   (ws + 13250000);   // 3,128
    int*    bstart = (int*)   (ws + 13260000);   // 3,128
    ushort* Wt1    = (ushort*)(ws + 13601024);   // 32,768
    ushort* Wt2    = (ushort*)(ws + 13633792);   // 32,768
    ushort* Wt3    = (ushort*)(ws + 13666560);   // 16,384
    int*    offT   = (int*)   (ws + 13700096);   // (NBK+1)*NBA*4 = 613,872
    ushort* g64    = (ushort*)(ws + 16000000);   // 12,800,000 (layer-3 gemm out)
    ushort* g      = (ushort*)(ws + 41600000);   // 25,600,000
    ushort* sbuf   = (ushort*)(ws + 67200000);   // 25,600,000  (total 92.8MB)

    // tmp aliases g (dead until gemm L1 writes it; build completes first).
    int2* tmp = (int2*)g;                        // NBA*EPB*8 = 12,845,056 <= 25.6MB

    // weight converts + gcount zeroing (replaces the memset dispatch)
    hipLaunchKernelGGL(wcvt_k, dim3(64), dim3(256), 0, stream,
                       W1, W2, W3, Wt1, Wt2, Wt3, gcount);

    // CSR build (counting sort by 128-row bucket)
    hipLaunchKernelGGL(binA_k, dim3(NBA), dim3(1024), 0, stream,
                       row, col, vals, tmp, gcount, offT);
    hipLaunchKernelGGL(bscan_k, dim3(1), dim3(1024), 0, stream, gcount, bstart, rowptr);
    hipLaunchKernelGGL(binB_k, dim3(NBK), dim3(256), 0, stream,
                       tmp, offT, bstart, rowptr, ep);

    const int GEMM_GRID = (N_NODES + 63) / 64;     // 1563
    const int SPMM_GRID = (N_NODES + 15) / 16;     // 6250

    // layer 1 (gemm reads fp32 x directly, converts in-register)
    hipLaunchKernelGGL((gemm_k<128, true>), dim3(GEMM_GRID), dim3(256), 0, stream, x, Wt1, b1, g);
    hipLaunchKernelGGL((spmm_k<128, true>), dim3(SPMM_GRID), dim3(256), 0, stream,
                       rowptr, ep, g, sbuf);
    // layer 2
    hipLaunchKernelGGL((gemm_k<128, false>), dim3(GEMM_GRID), dim3(256), 0, stream, sbuf, Wt2, b2, g);
    hipLaunchKernelGGL((spmm_k<128, true>), dim3(SPMM_GRID), dim3(256), 0, stream,
                       rowptr, ep, g, sbuf);
    // layer 3
    hipLaunchKernelGGL((gemm_k<64, false>), dim3(GEMM_GRID), dim3(256), 0, stream, sbuf, Wt3, b3, g64);
    hipLaunchKernelGGL((spmm_k<64, false>), dim3(SPMM_GRID), dim3(256), 0, stream,
                       rowptr, ep, g64, out);
}

// Round 10
// 293.852 us; speedup vs baseline: 1.4219x; 1.0274x over previous
//
#include <hip/hip_runtime.h>

#define N_NODES 100000
#define N_EDGES 1600000

#define NBK 782    // row buckets of 128 rows: ceil(100000/128)
#define EPB 8192   // edges per binA block
#define NBA 196    // binA blocks: 196*8192 = 1,605,632 >= N_EDGES
#define CAPE 4096  // LDS edge-stage capacity in binB (mean bucket = 2047, sigma ~45)

typedef __attribute__((ext_vector_type(8))) short short8;
typedef __attribute__((ext_vector_type(4))) float f32x4;

__device__ __forceinline__ ushort f2bf(float f) {
    uint u = __float_as_uint(f);
    return (ushort)((u + 0x7fff + ((u >> 16) & 1)) >> 16);   // RNE
}
__device__ __forceinline__ float bflo(uint p) { return __uint_as_float(p << 16); }
__device__ __forceinline__ float bfhi(uint p) { return __uint_as_float(p & 0xffff0000u); }

// ---------------- CSR build: two-pass counting sort by 128-row bucket ----------------

__global__ void __launch_bounds__(1024) binA_k(const int* __restrict__ row,
                                               const int* __restrict__ col,
                                               const float* __restrict__ vals,
                                               int2* __restrict__ tmp,
                                               int* __restrict__ gcount,
                                               int* __restrict__ offT) {
    __shared__ int h[NBK];
    __shared__ int cur[NBK];
    __shared__ int wpart[16];
    int t = threadIdx.x;
    int lane = t & 63;
    int base = blockIdx.x * EPB;

    // stage 8 edges/thread in registers (row/col/vals each read exactly once)
    int rr[8], cc[8];
    float vv[8];
#pragma unroll
    for (int u = 0; u < 8; ++u) {
        int e = base + u * 1024 + t;
        bool ok = (e < N_EDGES);
        rr[u] = ok ? row[e] : -1;
        cc[u] = ok ? col[e] : 0;
        vv[u] = ok ? vals[e] : 0.f;
    }

    if (t < NBK) h[t] = 0;
    __syncthreads();
#pragma unroll
    for (int u = 0; u < 8; ++u)
        if (rr[u] >= 0) atomicAdd(&h[rr[u] >> 7], 1);
    __syncthreads();
    int hv = (t < NBK) ? h[t] : 0;
    if (hv) atomicAdd(&gcount[t], hv);

    // wave-shuffle inclusive scan over thread order (h is zero past NBK)
    int v = hv;
    for (int off = 1; off < 64; off <<= 1) {
        int u2 = __shfl_up(v, off);
        if (lane >= off) v += u2;
    }
    if (lane == 63) wpart[t >> 6] = v;
    __syncthreads();
    if (t == 0) {
        int acc = 0;
#pragma unroll
        for (int i = 0; i < 16; ++i) { int w = wpart[i]; wpart[i] = acc; acc += w; }
    }
    __syncthreads();
    v += wpart[t >> 6];                      // inclusive prefix over h[0..t]
    if (t < NBK) {
        int ex = v - hv;
        cur[t] = ex;
        offT[t * NBA + blockIdx.x] = ex;
    }
    if (t == NBK - 1) offT[NBK * NBA + blockIdx.x] = v;  // row NBK = edges in block
    __syncthreads();
    // scatter into block-private region, grouped by bucket
#pragma unroll
    for (int u = 0; u < 8; ++u) {
        if (rr[u] >= 0) {
            int p = atomicAdd(&cur[rr[u] >> 7], 1);
            int2 w;
            w.x = ((rr[u] & 127) << 17) | cc[u];   // 7-bit row-in-bucket | 17-bit col
            w.y = __float_as_int(vv[u]);
            tmp[base + p] = w;
        }
    }
}

// exclusive scan of the 782 bucket totals -> bstart; also rowptr[N] = E
__global__ void __launch_bounds__(1024) bscan_k(const int* __restrict__ gcount,
                                                int* __restrict__ bstart,
                                                int* __restrict__ rowptr) {
    __shared__ int wpart[16];
    int t = threadIdx.x;
    int lane = t & 63;
    int g = (t < NBK) ? gcount[t] : 0;
    int v = g;
    for (int off = 1; off < 64; off <<= 1) {
        int u = __shfl_up(v, off);
        if (lane >= off) v += u;
    }
    if (lane == 63) wpart[t >> 6] = v;
    __syncthreads();
    if (t == 0) {
        int acc = 0;
#pragma unroll
        for (int i = 0; i < 16; ++i) { int w = wpart[i]; wpart[i] = acc; acc += w; }
    }
    __syncthreads();
    v += wpart[t >> 6];
    if (t < NBK) bstart[t] = v - g;
    if (t == 0) rowptr[N_NODES] = N_EDGES;
}

// Phase B: one block per bucket. 16-lane group per segment loads coalesced,
// histograms, packs into ebuf; pass 2 scatters flat from packed ebuf.

__global__ void __launch_bounds__(256) binB_k(const int2* __restrict__ tmp,
                                              const int* __restrict__ offT,
                                              const int* __restrict__ bstart,
                                              int* __restrict__ rowptr,
                                              int2* __restrict__ ep) {
    __shared__ int goff[NBA];
    __shared__ int scnt[NBA];
    __shared__ int sdst[NBA];
    __shared__ int h[128];
    __shared__ int cur[128];
    __shared__ int2 ebuf[CAPE];
    __shared__ int wpart[4];
    __shared__ int hp;
    int b = blockIdx.x, t = threadIdx.x;
    int lane = t & 63;

    int c = 0;
    if (t < NBA) {
        int o0 = offT[b * NBA + t];
        int o1 = offT[(b + 1) * NBA + t];
        c = o1 - o0;
        goff[t] = t * EPB + o0;
        scnt[t] = c;
    }
    // exclusive scan of segment counts (wave shuffle, 256 threads)
    int v = c;
    for (int off = 1; off < 64; off <<= 1) {
        int u = __shfl_up(v, off);
        if (lane >= off) v += u;
    }
    if (lane == 63) wpart[t >> 6] = v;
    if (t < 128) h[t] = 0;
    __syncthreads();
    if (t == 0) {
        int acc = 0;
#pragma unroll
        for (int i = 0; i < 4; ++i) { int w = wpart[i]; wpart[i] = acc; acc += w; }
    }
    __syncthreads();
    v += wpart[t >> 6];
    if (t < NBA) sdst[t] = v - c;
    __syncthreads();

    // pass 1: 16-lane group per segment: coalesced load, LDS hist, pack into ebuf
    int grp = t >> 4, gl = t & 15;            // 16 groups of 16 lanes
    for (int s = grp; s < NBA; s += 16) {
        int n = scnt[s], go = goff[s], dd = sdst[s];
        for (int i = gl; i < n; i += 16) {
            int2 e = tmp[go + i];
            atomicAdd(&h[e.x >> 17], 1);
            ebuf[dd + i] = e;
        }
    }
    __syncthreads();
    // exclusive scan over 128 bins (2 waves + 1 partial)
    int hv = (t < 128) ? h[t] : 0;
    int sv = hv;
    for (int off = 1; off < 64; off <<= 1) {
        int u = __shfl_up(sv, off);
        if (lane >= off) sv += u;
    }
    if (t == 63) hp = sv;
    __syncthreads();
    int bs = bstart[b];
    if (t < 128) {
        int inc = sv + ((t >= 64) ? hp : 0);
        int ex = inc - hv;
        cur[t] = ex;
        int r = (b << 7) + t;
        if (r < N_NODES) rowptr[r] = bs + ex;
    }
    __syncthreads();
    // pass 2: flat scatter from packed ebuf to final CSR positions
    int T = sdst[NBA - 1] + scnt[NBA - 1];
    for (int j = t; j < T; j += 256) {
        int2 e = ebuf[j];
        int p = atomicAdd(&cur[e.x >> 17], 1);
        int2 w;
        w.x = e.x & 0x1ffff;
        w.y = e.y;
        ep[bs + p] = w;
    }
}

// ---------------- converts ----------------

// transpose-convert all three weight matrices: Wt[n][k] = bf16(W[k][n]).
// Also zeroes gcount (this kernel launches FIRST, replacing the memset dispatch).
__global__ void wcvt_k(const float* __restrict__ W1, const float* __restrict__ W2,
                       const float* __restrict__ W3, ushort* __restrict__ Wt1,
                       ushort* __restrict__ Wt2, ushort* __restrict__ Wt3,
                       int* __restrict__ gcount) {
    int i = blockIdx.x * 256 + threadIdx.x;
    if (i < NBK) gcount[i] = 0;
    if (i < 16384) {
        int n = i >> 7, k = i & 127;
        Wt1[i] = f2bf(W1[k * 128 + n]);
        Wt2[i] = f2bf(W2[k * 128 + n]);
    }
    if (i < 8192) {
        int n = i >> 7, k = i & 127;
        Wt3[i] = f2bf(W3[k * 64 + n]);
    }
}

// ---------------- GEMM: Y[r, 0..DN) = bf16( X[r,:] @ Wt^T + bias ) ----------------

template <int DN, bool AF32>
__global__ void __launch_bounds__(256) gemm_k(const void* __restrict__ Xa,
                                              const ushort* __restrict__ Wt,
                                              const float* __restrict__ bias,
                                              ushort* __restrict__ Y) {
    constexpr int NT = DN / 16;
    const ushort* Xb = (const ushort*)Xa;
    const float* Xf = (const float*)Xa;
    int wv = threadIdx.x >> 6;
    int l = threadIdx.x & 63;
    int lg = l >> 4, lm = l & 15;
    int rbase = blockIdx.x * 64 + wv * 16;

    int arow = rbase + lm;
    if (arow > N_NODES - 1) arow = N_NODES - 1;     // clamp (stores predicated)

    f32x4 acc[NT];
#pragma unroll
    for (int n = 0; n < NT; n++) acc[n] = (f32x4){0.f, 0.f, 0.f, 0.f};

#pragma unroll
    for (int kk = 0; kk < 4; ++kk) {
        short8 a;
        if constexpr (AF32) {
            const float* ap = Xf + (size_t)arow * 128 + kk * 32 + lg * 8;
            float4 u = *(const float4*)ap;
            float4 v = *(const float4*)(ap + 4);
            a = (short8){(short)f2bf(u.x), (short)f2bf(u.y), (short)f2bf(u.z), (short)f2bf(u.w),
                         (short)f2bf(v.x), (short)f2bf(v.y), (short)f2bf(v.z), (short)f2bf(v.w)};
        } else {
            a = *(const short8*)(Xb + (size_t)arow * 128 + kk * 32 + lg * 8);
        }
#pragma unroll
        for (int n = 0; n < NT; ++n) {
            short8 b = *(const short8*)(Wt + (size_t)(n * 16 + lm) * 128 + kk * 32 + lg * 8);
            acc[n] = __builtin_amdgcn_mfma_f32_16x16x32_bf16(a, b, acc[n], 0, 0, 0);
        }
    }

    int r0 = rbase + lg * 4;
#pragma unroll
    for (int n = 0; n < NT; ++n) {
        int c = n * 16 + lm;
        float bj = bias[c];
#pragma unroll
        for (int i = 0; i < 4; ++i) {
            int r = r0 + i;
            if (r < N_NODES) Y[(size_t)r * DN + c] = f2bf(acc[n][i] + bj);
        }
    }
}

// ---------------- SpMM (CSR; one 16-lane group per row; ep staged via LDS) -----------
// A block's 16 rows own a CONTIGUOUS ep slice (~256 edges): stage it coalesced into
// LDS (~4 VMEM instrs instead of ~256 broadcast loads), then the inner loop reads
// edges via LDS broadcast. Gathers (the structural-minimum VMEM stream) unchanged.
// Overflow blocks (>CAP edges, ~never for random graphs) fall back to global reads.

#define SPMM_BODY(EPREAD)                                                     \
    if (D == 128) {                                                           \
        const uint4* xp = (const uint4*)xb;                                   \
        float a0 = 0.f, a1 = 0.f, a2 = 0.f, a3 = 0.f;                         \
        float a4 = 0.f, a5 = 0.f, a6 = 0.f, a7 = 0.f;                         \
        int i = s;                                                            \
        for (; i + 4 <= e; i += 4) {                                          \
            int2 e0 = EPREAD(i), e1 = EPREAD(i + 1);                          \
            int2 e2 = EPREAD(i + 2), e3 = EPREAD(i + 3);                      \
            uint4 x0 = xp[e0.x * 16 + hl];                                    \
            uint4 x1 = xp[e1.x * 16 + hl];                                    \
            uint4 x2 = xp[e2.x * 16 + hl];                                    \
            uint4 x3 = xp[e3.x * 16 + hl];                                    \
            float v0 = __int_as_float(e0.y), v1 = __int_as_float(e1.y);       \
            float v2 = __int_as_float(e2.y), v3 = __int_as_float(e3.y);       \
            a0 = fmaf(v0, bflo(x0.x), a0); a1 = fmaf(v0, bfhi(x0.x), a1);     \
            a2 = fmaf(v0, bflo(x0.y), a2); a3 = fmaf(v0, bfhi(x0.y), a3);     \
            a4 = fmaf(v0, bflo(x0.z), a4); a5 = fmaf(v0, bfhi(x0.z), a5);     \
            a6 = fmaf(v0, bflo(x0.w), a6); a7 = fmaf(v0, bfhi(x0.w), a7);     \
            a0 = fmaf(v1, bflo(x1.x), a0); a1 = fmaf(v1, bfhi(x1.x), a1);     \
            a2 = fmaf(v1, bflo(x1.y), a2); a3 = fmaf(v1, bfhi(x1.y), a3);     \
            a4 = fmaf(v1, bflo(x1.z), a4); a5 = fmaf(v1, bfhi(x1.z), a5);     \
            a6 = fmaf(v1, bflo(x1.w), a6); a7 = fmaf(v1, bfhi(x1.w), a7);     \
            a0 = fmaf(v2, bflo(x2.x), a0); a1 = fmaf(v2, bfhi(x2.x), a1);     \
            a2 = fmaf(v2, bflo(x2.y), a2); a3 = fmaf(v2, bfhi(x2.y), a3);     \
            a4 = fmaf(v2, bflo(x2.z), a4); a5 = fmaf(v2, bfhi(x2.z), a5);     \
            a6 = fmaf(v2, bflo(x2.w), a6); a7 = fmaf(v2, bfhi(x2.w), a7);     \
            a0 = fmaf(v3, bflo(x3.x), a0); a1 = fmaf(v3, bfhi(x3.x), a1);     \
            a2 = fmaf(v3, bflo(x3.y), a2); a3 = fmaf(v3, bfhi(x3.y), a3);     \
            a4 = fmaf(v3, bflo(x3.z), a4); a5 = fmaf(v3, bfhi(x3.z), a5);     \
            a6 = fmaf(v3, bflo(x3.w), a6); a7 = fmaf(v3, bfhi(x3.w), a7);     \
        }                                                                     \
        for (; i < e; ++i) {                                                  \
            int2 e0 = EPREAD(i);                                              \
            uint4 x0 = xp[e0.x * 16 + hl];                                    \
            float v0 = __int_as_float(e0.y);                                  \
            a0 = fmaf(v0, bflo(x0.x), a0); a1 = fmaf(v0, bfhi(x0.x), a1);     \
            a2 = fmaf(v0, bflo(x0.y), a2); a3 = fmaf(v0, bfhi(x0.y), a3);     \
            a4 = fmaf(v0, bflo(x0.z), a4); a5 = fmaf(v0, bfhi(x0.z), a5);     \
            a6 = fmaf(v0, bflo(x0.w), a6); a7 = fmaf(v0, bfhi(x0.w), a7);     \
        }                                                                     \
        if (RELU) {                                                           \
            a0 = fmaxf(a0, 0.f); a1 = fmaxf(a1, 0.f);                         \
            a2 = fmaxf(a2, 0.f); a3 = fmaxf(a3, 0.f);                         \
            a4 = fmaxf(a4, 0.f); a5 = fmaxf(a5, 0.f);                         \
            a6 = fmaxf(a6, 0.f); a7 = fmaxf(a7, 0.f);                         \
        }                                                                     \
        uint4 o;                                                              \
        o.x = (uint)f2bf(a0) | ((uint)f2bf(a1) << 16);                        \
        o.y = (uint)f2bf(a2) | ((uint)f2bf(a3) << 16);                        \
        o.z = (uint)f2bf(a4) | ((uint)f2bf(a5) << 16);                        \
        o.w = (uint)f2bf(a6) | ((uint)f2bf(a7) << 16);                        \
        ((uint4*)y)[w * 16 + hl] = o;                                         \
    } else {                                                                  \
        const uint2* xp = (const uint2*)xb;                                   \
        float a0 = 0.f, a1 = 0.f, a2 = 0.f, a3 = 0.f;                         \
        int i = s;                                                            \
        for (; i + 4 <= e; i += 4) {                                          \
            int2 e0 = EPREAD(i), e1 = EPREAD(i + 1);                          \
            int2 e2 = EPREAD(i + 2), e3 = EPREAD(i + 3);                      \
            uint2 x0 = xp[e0.x * 16 + hl];                                    \
            uint2 x1 = xp[e1.x * 16 + hl];                                    \
            uint2 x2 = xp[e2.x * 16 + hl];                                    \
            uint2 x3 = xp[e3.x * 16 + hl];                                    \
            float v0 = __int_as_float(e0.y), v1 = __int_as_float(e1.y);       \
            float v2 = __int_as_float(e2.y), v3 = __int_as_float(e3.y);       \
            a0 = fmaf(v0, bflo(x0.x), a0); a1 = fmaf(v0, bfhi(x0.x), a1);     \
            a2 = fmaf(v0, bflo(x0.y), a2); a3 = fmaf(v0, bfhi(x0.y), a3);     \
            a0 = fmaf(v1, bflo(x1.x), a0); a1 = fmaf(v1, bfhi(x1.x), a1);     \
            a2 = fmaf(v1, bflo(x1.y), a2); a3 = fmaf(v1, bfhi(x1.y), a3);     \
            a0 = fmaf(v2, bflo(x2.x), a0); a1 = fmaf(v2, bfhi(x2.x), a1);     \
            a2 = fmaf(v2, bflo(x2.y), a2); a3 = fmaf(v2, bfhi(x2.y), a3);     \
            a0 = fmaf(v3, bflo(x3.x), a0); a1 = fmaf(v3, bfhi(x3.x), a1);     \
            a2 = fmaf(v3, bflo(x3.y), a2); a3 = fmaf(v3, bfhi(x3.y), a3);     \
        }                                                                     \
        for (; i < e; ++i) {                                                  \
            int2 e0 = EPREAD(i);                                              \
            uint2 x0 = xp[e0.x * 16 + hl];                                    \
            float v0 = __int_as_float(e0.y);                                  \
            a0 = fmaf(v0, bflo(x0.x), a0); a1 = fmaf(v0, bfhi(x0.x), a1);     \
            a2 = fmaf(v0, bflo(x0.y), a2); a3 = fmaf(v0, bfhi(x0.y), a3);     \
        }                                                                     \
        if (RELU) {                                                           \
            a0 = fmaxf(a0, 0.f); a1 = fmaxf(a1, 0.f);                         \
            a2 = fmaxf(a2, 0.f); a3 = fmaxf(a3, 0.f);                         \
        }                                                                     \
        float4 o; o.x = a0; o.y = a1; o.z = a2; o.w = a3;                     \
        ((float4*)y)[w * 16 + hl] = o;                                        \
    }

template <int D, bool RELU>
__global__ void __launch_bounds__(256) spmm_k(const int* __restrict__ rowptr,
                                              const int2* __restrict__ ep,
                                              const ushort* __restrict__ xb,
                                              void* __restrict__ y) {
    constexpr int CAP = 1536;                  // 12 KB LDS; block mean = 256 edges
    __shared__ int2 eb[CAP];
    __shared__ int sh_s0, sh_n;
    int t = threadIdx.x;
    int g = t >> 4, hl = t & 15;
    int rbase = blockIdx.x * 16;
    int w = rbase + g;

    if (t == 0) {
        int s0 = rowptr[rbase];
        int rend = rbase + 16; if (rend > N_NODES) rend = N_NODES;
        sh_s0 = s0;
        sh_n = rowptr[rend] - s0;
    }
    __syncthreads();
    int s0 = sh_s0, n = sh_n;
    bool inlds = (n <= CAP);
    if (inlds) {
        for (int j = t; j < n; j += 256) eb[j] = ep[s0 + j];   // coalesced stage
    }
    __syncthreads();
    if (w >= N_NODES) return;
    int s = rowptr[w], e = rowptr[w + 1];

    if (inlds) {
        s -= s0; e -= s0;
#define EPL(i) eb[i]
        SPMM_BODY(EPL)
#undef EPL
    } else {                                   // overflow fallback (rare)
#define EPG(i) ep[i]
        SPMM_BODY(EPG)
#undef EPG
    }
}

// ---------------- launch ----------------

extern "C" void kernel_launch(void* const* d_in, const int* in_sizes, int n_in,
                              void* d_out, int out_size, void* d_ws, size_t ws_size,
                              hipStream_t stream) {
    const float* x    = (const float*)d_in[0];
    const float* vals = (const float*)d_in[1];
    const float* W1   = (const float*)d_in[2];
    const float* b1   = (const float*)d_in[3];
    const float* W2   = (const float*)d_in[4];
    const float* b2   = (const float*)d_in[5];
    const float* W3   = (const float*)d_in[6];
    const float* b3   = (const float*)d_in[7];
    const int* row    = (const int*)d_in[8];
    const int* col    = (const int*)d_in[9];
    float* out = (float*)d_out;

    char* ws = (char*)d_ws;
    int2*   ep     = (int2*)  (ws + 0);          // 12,800,000
    int*    rowptr = (int*)   (ws + 12800000);   // 400,004
    int*    gcount = (int*)   (ws + 13250000);   // 3,128
    int*    bstart = (int*)   (ws + 13260000);   // 3,128
    ushort* Wt1    = (ushort*)(ws + 13601024);   // 32,768
    ushort* Wt2    = (ushort*)(ws + 13633792);   // 32,768
    ushort* Wt3    = (ushort*)(ws + 13666560);   // 16,384
    int*    offT   = (int*)   (ws + 13700096);   // (NBK+1)*NBA*4 = 613,872
    ushort* g64    = (ushort*)(ws + 16000000);   // 12,800,000 (layer-3 gemm out)
    ushort* g      = (ushort*)(ws + 41600000);   // 25,600,000
    ushort* sbuf   = (ushort*)(ws + 67200000);   // 25,600,000  (total 92.8MB)

    // tmp aliases g (dead until gemm L1 writes it; build completes first).
    int2* tmp = (int2*)g;                        // NBA*EPB*8 = 12,845,056 <= 25.6MB

    // weight converts + gcount zeroing (replaces the memset dispatch)
    hipLaunchKernelGGL(wcvt_k, dim3(64), dim3(256), 0, stream,
                       W1, W2, W3, Wt1, Wt2, Wt3, gcount);

    // CSR build (counting sort by 128-row bucket)
    hipLaunchKernelGGL(binA_k, dim3(NBA), dim3(1024), 0, stream,
                       row, col, vals, tmp, gcount, offT);
    hipLaunchKernelGGL(bscan_k, dim3(1), dim3(1024), 0, stream, gcount, bstart, rowptr);
    hipLaunchKernelGGL(binB_k, dim3(NBK), dim3(256), 0, stream,
                       tmp, offT, bstart, rowptr, ep);

    const int GEMM_GRID = (N_NODES + 63) / 64;     // 1563
    const int SPMM_GRID = (N_NODES + 15) / 16;     // 6250

    // layer 1 (gemm reads fp32 x directly, converts in-register)
    hipLaunchKernelGGL((gemm_k<128, true>), dim3(GEMM_GRID), dim3(256), 0, stream, x, Wt1, b1, g);
    hipLaunchKernelGGL((spmm_k<128, true>), dim3(SPMM_GRID), dim3(256), 0, stream,
                       rowptr, ep, g, sbuf);
    // layer 2
    hipLaunchKernelGGL((gemm_k<128, false>), dim3(GEMM_GRID), dim3(256), 0, stream, sbuf, Wt2, b2, g);
    hipLaunchKernelGGL((spmm_k<128, true>), dim3(SPMM_GRID), dim3(256), 0, stream,
                       rowptr, ep, g, sbuf);
    // layer 3
    hipLaunchKernelGGL((gemm_k<64, false>), dim3(GEMM_GRID), dim3(256), 0, stream, sbuf, Wt3, b3, g64);
    hipLaunchKernelGGL((spmm_k<64, false>), dim3(SPMM_GRID), dim3(256), 0, stream,
                       rowptr, ep, g64, out);
}